// Round 1
// baseline (358.727 us; speedup 1.0000x reference)
//
#include <hip/hip_runtime.h>
#include <hip/hip_bf16.h>

#define DIN 1024
#define NH 16
#define HD 64
#define SEQ 2048
#define NB 2

typedef __attribute__((ext_vector_type(8))) short bf16x8;
typedef __attribute__((ext_vector_type(4))) float f32x4;

__device__ inline short f2bf(float f) {
  union { float f; unsigned u; } v; v.f = f;
  unsigned r = v.u + 0x7fff + ((v.u >> 16) & 1);
  return (short)(r >> 16);
}

// fp32 [R][C] -> bf16 [C][R], per-z slab of R*C elements
__global__ __launch_bounds__(256) void wt_kernel(const float* __restrict__ in,
                                                 short* __restrict__ out, int R, int C) {
  __shared__ float tile[64][65];
  int r0 = blockIdx.y * 64, c0 = blockIdx.x * 64;
  size_t zoff = (size_t)blockIdx.z * R * C;
  in += zoff; out += zoff;
  int t = threadIdx.x;
  int r = t >> 2, cc = (t & 3) * 16;
#pragma unroll
  for (int j = 0; j < 16; ++j) tile[r][cc + j] = in[(size_t)(r0 + r) * C + c0 + cc + j];
  __syncthreads();
  int c = t >> 2, rr = (t & 3) * 16;
#pragma unroll
  for (int j = 0; j < 16; ++j) out[(size_t)(c0 + c) * R + r0 + rr + j] = f2bf(tile[rr + j][c]);
}

// QKV projection: X[4096,1024] fp32 x Wt[h][64 n][1024 d] bf16 + bias -> bf16
// q,k: [B,H,S,64] ; v: transposed [B,H,64,S]
__global__ __launch_bounds__(256) void proj_kernel(
    const float* __restrict__ Q, const float* __restrict__ K, const float* __restrict__ V,
    const short* __restrict__ wtq, const short* __restrict__ wtk, const short* __restrict__ wtv,
    const float* __restrict__ bq, const float* __restrict__ bk, const float* __restrict__ bv,
    short* __restrict__ qb, short* __restrict__ kb, short* __restrict__ vt) {
  int mt = blockIdx.x, h = blockIdx.y, tz = blockIdx.z;
  const float* X = tz == 0 ? Q : (tz == 1 ? K : V);
  const short* Wt = (tz == 0 ? wtq : (tz == 1 ? wtk : wtv)) + h * (HD * DIN);
  const float* bias = (tz == 0 ? bq : (tz == 1 ? bk : bv)) + h * HD;
  short* out = tz == 0 ? qb : (tz == 1 ? kb : vt);

  __shared__ __align__(16) short Al[64][40];
  __shared__ __align__(16) short Bl[64][40];

  int t = threadIdx.x;
  int wid = t >> 6, lane = t & 63, lrow = lane & 15, lhi = lane >> 4;
  int row0 = mt * 64;

  f32x4 acc[4] = {};
  int ar = t >> 2, ac = (t & 3) * 8;
  const float* aptr = X + (size_t)(row0 + ar) * DIN + ac;
  const short* bptr = Wt + (size_t)ar * DIN + ac;

  for (int kk = 0; kk < DIN; kk += 32) {
    float4 x0 = *(const float4*)(aptr + kk);
    float4 x1 = *(const float4*)(aptr + kk + 4);
    bf16x8 av;
    av[0] = f2bf(x0.x); av[1] = f2bf(x0.y); av[2] = f2bf(x0.z); av[3] = f2bf(x0.w);
    av[4] = f2bf(x1.x); av[5] = f2bf(x1.y); av[6] = f2bf(x1.z); av[7] = f2bf(x1.w);
    *(bf16x8*)&Al[ar][ac] = av;
    *(bf16x8*)&Bl[ar][ac] = *(const bf16x8*)(bptr + kk);
    __syncthreads();
    bf16x8 a = *(bf16x8*)&Al[wid * 16 + lrow][lhi * 8];
#pragma unroll
    for (int tt = 0; tt < 4; ++tt) {
      bf16x8 bfr = *(bf16x8*)&Bl[tt * 16 + lrow][lhi * 8];
      acc[tt] = __builtin_amdgcn_mfma_f32_16x16x32_bf16(a, bfr, acc[tt], 0, 0, 0);
    }
    __syncthreads();
  }
#pragma unroll
  for (int tt = 0; tt < 4; ++tt) {
    int col = tt * 16 + lrow;
    float bval = bias[col];
#pragma unroll
    for (int i = 0; i < 4; ++i) {
      int r = row0 + wid * 16 + lhi * 4 + i;
      int bb = r >> 11, s = r & 2047;
      float val = acc[tt][i] + bval;
      size_t addr;
      if (tz == 2) addr = ((size_t)(bb * NH + h) * HD + col) * SEQ + s;
      else addr = ((size_t)(bb * NH + h) * SEQ + s) * HD + col;
      out[addr] = f2bf(val);
    }
  }
}

// flash attention: 64 q-rows per block (4 waves x 16), KV tiles of 64
__global__ __launch_bounds__(256) void attn_kernel(
    const short* __restrict__ qb, const short* __restrict__ kb,
    const short* __restrict__ vt, short* __restrict__ ob) {
  int qt = blockIdx.x, h = blockIdx.y, b = blockIdx.z;
  int t = threadIdx.x;
  int wid = t >> 6, lane = t & 63, lrow = lane & 15, lhi = lane >> 4;
  __shared__ __align__(16) short kl[64][72];
  __shared__ __align__(16) short vl[64][72];
  __shared__ __align__(16) short pl[64][72];

  size_t bh = (size_t)(b * NH + h);
  const short* qbase = qb + (bh * SEQ + qt * 64) * HD;
  bf16x8 aq0 = *(const bf16x8*)(qbase + (wid * 16 + lrow) * HD + lhi * 8);
  bf16x8 aq1 = *(const bf16x8*)(qbase + (wid * 16 + lrow) * HD + 32 + lhi * 8);

  const short* kbase = kb + bh * (size_t)SEQ * HD;
  const short* vbase = vt + bh * (size_t)HD * SEQ;

  f32x4 oacc[4] = {};
  float mrun[4], lrun[4];
#pragma unroll
  for (int i = 0; i < 4; ++i) { mrun[i] = -1e30f; lrun[i] = 0.f; }

  int sr = t >> 2, sc0 = (t & 3) * 16;
  for (int t0 = 0; t0 < SEQ; t0 += 64) {
    const bf16x8* ks = (const bf16x8*)(kbase + (size_t)(t0 + sr) * HD + sc0);
    *(bf16x8*)&kl[sr][sc0] = ks[0];
    *(bf16x8*)&kl[sr][sc0 + 8] = ks[1];
    const bf16x8* vs = (const bf16x8*)(vbase + (size_t)sr * SEQ + t0 + sc0);
    *(bf16x8*)&vl[sr][sc0] = vs[0];
    *(bf16x8*)&vl[sr][sc0 + 8] = vs[1];
    __syncthreads();

    f32x4 sc[4];
#pragma unroll
    for (int tt = 0; tt < 4; ++tt) {
      f32x4 z = {};
      bf16x8 b0 = *(bf16x8*)&kl[tt * 16 + lrow][lhi * 8];
      bf16x8 b1 = *(bf16x8*)&kl[tt * 16 + lrow][32 + lhi * 8];
      z = __builtin_amdgcn_mfma_f32_16x16x32_bf16(aq0, b0, z, 0, 0, 0);
      z = __builtin_amdgcn_mfma_f32_16x16x32_bf16(aq1, b1, z, 0, 0, 0);
      sc[tt] = z;
    }
#pragma unroll
    for (int i = 0; i < 4; ++i) {
      float s0 = sc[0][i] * 0.125f, s1 = sc[1][i] * 0.125f;
      float s2 = sc[2][i] * 0.125f, s3 = sc[3][i] * 0.125f;
      float mx = fmaxf(fmaxf(s0, s1), fmaxf(s2, s3));
      mx = fmaxf(mx, __shfl_xor(mx, 1));
      mx = fmaxf(mx, __shfl_xor(mx, 2));
      mx = fmaxf(mx, __shfl_xor(mx, 4));
      mx = fmaxf(mx, __shfl_xor(mx, 8));
      float mnew = fmaxf(mrun[i], mx);
      float corr = __expf(mrun[i] - mnew);
      mrun[i] = mnew;
      float p0 = __expf(s0 - mnew), p1 = __expf(s1 - mnew);
      float p2 = __expf(s2 - mnew), p3 = __expf(s3 - mnew);
      float ps = p0 + p1 + p2 + p3;
      ps += __shfl_xor(ps, 1); ps += __shfl_xor(ps, 2);
      ps += __shfl_xor(ps, 4); ps += __shfl_xor(ps, 8);
      lrun[i] = lrun[i] * corr + ps;
#pragma unroll
      for (int tt = 0; tt < 4; ++tt) oacc[tt][i] *= corr;
      int rr = wid * 16 + lhi * 4 + i;
      pl[rr][0 + lrow] = f2bf(p0);
      pl[rr][16 + lrow] = f2bf(p1);
      pl[rr][32 + lrow] = f2bf(p2);
      pl[rr][48 + lrow] = f2bf(p3);
    }
    __syncthreads();
    bf16x8 ap0 = *(bf16x8*)&pl[wid * 16 + lrow][lhi * 8];
    bf16x8 ap1 = *(bf16x8*)&pl[wid * 16 + lrow][32 + lhi * 8];
#pragma unroll
    for (int tt = 0; tt < 4; ++tt) {
      bf16x8 b0 = *(bf16x8*)&vl[tt * 16 + lrow][lhi * 8];
      bf16x8 b1 = *(bf16x8*)&vl[tt * 16 + lrow][32 + lhi * 8];
      oacc[tt] = __builtin_amdgcn_mfma_f32_16x16x32_bf16(ap0, b0, oacc[tt], 0, 0, 0);
      oacc[tt] = __builtin_amdgcn_mfma_f32_16x16x32_bf16(ap1, b1, oacc[tt], 0, 0, 0);
    }
    __syncthreads();
  }
#pragma unroll
  for (int tt = 0; tt < 4; ++tt) {
    int col = tt * 16 + lrow;
#pragma unroll
    for (int i = 0; i < 4; ++i) {
      int rr = wid * 16 + lhi * 4 + i;
      float val = oacc[tt][i] / lrun[i];
      size_t addr = ((size_t)(b * SEQ + qt * 64 + rr)) * DIN + h * HD + col;
      ob[addr] = f2bf(val);
    }
  }
}

// out projection: ob[4096,1024] bf16 x Wot[1024 n][1024 d] bf16 + bo -> fp32
__global__ __launch_bounds__(256) void oproj_kernel(
    const short* __restrict__ ob, const short* __restrict__ wto,
    const float* __restrict__ bo, float* __restrict__ out) {
  int mt = blockIdx.x, nt = blockIdx.y;
  int row0 = mt * 64, col0 = nt * 64;
  __shared__ __align__(16) short Al[64][40];
  __shared__ __align__(16) short Bl[64][40];
  int t = threadIdx.x;
  int wid = t >> 6, lane = t & 63, lrow = lane & 15, lhi = lane >> 4;
  f32x4 acc[4] = {};
  int ar = t >> 2, ac = (t & 3) * 8;
  const short* aptr = ob + (size_t)(row0 + ar) * DIN + ac;
  const short* bptr = wto + (size_t)(col0 + ar) * DIN + ac;
  for (int kk = 0; kk < DIN; kk += 32) {
    *(bf16x8*)&Al[ar][ac] = *(const bf16x8*)(aptr + kk);
    *(bf16x8*)&Bl[ar][ac] = *(const bf16x8*)(bptr + kk);
    __syncthreads();
    bf16x8 a = *(bf16x8*)&Al[wid * 16 + lrow][lhi * 8];
#pragma unroll
    for (int tt = 0; tt < 4; ++tt) {
      bf16x8 bfr = *(bf16x8*)&Bl[tt * 16 + lrow][lhi * 8];
      acc[tt] = __builtin_amdgcn_mfma_f32_16x16x32_bf16(a, bfr, acc[tt], 0, 0, 0);
    }
    __syncthreads();
  }
#pragma unroll
  for (int tt = 0; tt < 4; ++tt) {
    int col = col0 + tt * 16 + lrow;
    float bval = bo[col];
#pragma unroll
    for (int i = 0; i < 4; ++i) {
      int r = row0 + wid * 16 + lhi * 4 + i;
      out[(size_t)r * DIN + col] = acc[tt][i] + bval;
    }
  }
}

extern "C" void kernel_launch(void* const* d_in, const int* in_sizes, int n_in,
                              void* d_out, int out_size, void* d_ws, size_t ws_size,
                              hipStream_t stream) {
  const float* Q  = (const float*)d_in[0];
  const float* K  = (const float*)d_in[1];
  const float* V  = (const float*)d_in[2];
  const float* Wq = (const float*)d_in[3];
  const float* bq = (const float*)d_in[4];
  const float* Wk = (const float*)d_in[5];
  const float* bk = (const float*)d_in[6];
  const float* Wv = (const float*)d_in[7];
  const float* bv = (const float*)d_in[8];
  const float* Wo = (const float*)d_in[9];
  const float* bo = (const float*)d_in[10];
  float* out = (float*)d_out;

  short* ws = (short*)d_ws;
  const size_t NQKV = (size_t)NB * NH * SEQ * HD;  // 4194304
  short* qbuf = ws;
  short* kbuf = qbuf + NQKV;
  short* vtb  = kbuf + NQKV;
  short* obuf = vtb + NQKV;
  short* wtq  = obuf + NQKV;
  short* wtk  = wtq + (size_t)NH * HD * DIN;
  short* wtv  = wtk + (size_t)NH * HD * DIN;
  short* wto  = wtv + (size_t)NH * HD * DIN;

  wt_kernel<<<dim3(1, 16, 16), 256, 0, stream>>>(Wq, wtq, DIN, HD);
  wt_kernel<<<dim3(1, 16, 16), 256, 0, stream>>>(Wk, wtk, DIN, HD);
  wt_kernel<<<dim3(1, 16, 16), 256, 0, stream>>>(Wv, wtv, DIN, HD);
  wt_kernel<<<dim3(16, 16, 1), 256, 0, stream>>>(Wo, wto, DIN, DIN);
  proj_kernel<<<dim3(64, 16, 3), 256, 0, stream>>>(Q, K, V, wtq, wtk, wtv,
                                                   bq, bk, bv, qbuf, kbuf, vtb);
  attn_kernel<<<dim3(32, 16, 2), 256, 0, stream>>>(qbuf, kbuf, vtb, obuf);
  oproj_kernel<<<dim3(64, 16), 256, 0, stream>>>(obuf, wto, bo, out);
}

// Round 3
// 313.927 us; speedup vs baseline: 1.1427x; 1.1427x over previous
//
#include <hip/hip_runtime.h>
#include <hip/hip_bf16.h>

#define DIN 1024
#define NH 16
#define HD 64
#define SEQ 2048
#define NB 2

typedef __attribute__((ext_vector_type(8))) short bf16x8;
typedef __attribute__((ext_vector_type(4))) float f32x4;

__device__ inline short f2bf(float f) {
  union { float f; unsigned u; } v; v.f = f;
  unsigned r = v.u + 0x7fff + ((v.u >> 16) & 1);
  return (short)(r >> 16);
}

__device__ __forceinline__ void gload_lds16(const void* g, void* l) {
  __builtin_amdgcn_global_load_lds(
      (const __attribute__((address_space(1))) unsigned*)g,
      (__attribute__((address_space(3))) unsigned*)l, 16, 0, 0);
}

// Wq/Wk/Wv [H][1024][64] fp32 -> Wt [3][H][64][1024] bf16 (transposed per head)
__global__ __launch_bounds__(256) void wt3_kernel(
    const float* __restrict__ Wq, const float* __restrict__ Wk, const float* __restrict__ Wv,
    short* __restrict__ out) {
  int zz = blockIdx.z; int which = zz >> 4, h = zz & 15;
  const float* in = (which == 0 ? Wq : (which == 1 ? Wk : Wv)) + (size_t)h * (DIN * HD);
  short* o = out + (size_t)which * (NH * HD * DIN) + (size_t)h * (HD * DIN);
  __shared__ float tile[64][65];
  int r0 = blockIdx.y * 64;
  int t = threadIdx.x;
  int r = t >> 2, cc = (t & 3) * 16;
#pragma unroll
  for (int j = 0; j < 16; ++j) tile[r][cc + j] = in[(size_t)(r0 + r) * HD + cc + j];
  __syncthreads();
  int c = t >> 2, rr = (t & 3) * 16;
#pragma unroll
  for (int j = 0; j < 16; ++j) o[(size_t)c * DIN + r0 + rr + j] = f2bf(tile[rr + j][c]);
}

// Wo [1024][1024] fp32 -> Wot [1024 n][1024 k] bf16
__global__ __launch_bounds__(256) void wt_kernel(const float* __restrict__ in,
                                                 short* __restrict__ out, int R, int C) {
  __shared__ float tile[64][65];
  int r0 = blockIdx.y * 64, c0 = blockIdx.x * 64;
  int t = threadIdx.x;
  int r = t >> 2, cc = (t & 3) * 16;
#pragma unroll
  for (int j = 0; j < 16; ++j) tile[r][cc + j] = in[(size_t)(r0 + r) * C + c0 + cc + j];
  __syncthreads();
  int c = t >> 2, rr = (t & 3) * 16;
#pragma unroll
  for (int j = 0; j < 16; ++j) out[(size_t)(c0 + c) * R + r0 + rr + j] = f2bf(tile[rr + j][c]);
}

// 128x128-tile GEMM: A = fp32 X (reg-staged + cvt), B = bf16 Wt via global_load_lds.
// q,k row-major [B,H,S,64]; v transposed [B,H,64,S].
__global__ __launch_bounds__(256) void proj_kernel(
    const float* __restrict__ Q, const float* __restrict__ K, const float* __restrict__ V,
    const short* __restrict__ wt,
    const float* __restrict__ bq, const float* __restrict__ bk, const float* __restrict__ bv,
    short* __restrict__ qb, short* __restrict__ kb, short* __restrict__ vt) {
  int mt = blockIdx.x, nt = blockIdx.y, z = blockIdx.z;
  const float* X = z == 0 ? Q : (z == 1 ? K : V);
  const short* Bt = wt + (size_t)z * (DIN * DIN);
  const float* bias = z == 0 ? bq : (z == 1 ? bk : bv);

  __shared__ __align__(16) short Al[128 * 32];
  __shared__ __align__(16) short Bl[128 * 32];

  int t = threadIdx.x, wid = t >> 6, lane = t & 63;
  int lrow = lane & 15, lhi = lane >> 4;
  int wr = wid >> 1, wc = wid & 1;
  int row0 = mt * 128, col0 = nt * 128;

  // A: fp32 -> bf16 reg-staged. thread t: row t>>1, cols (t&1)*16 .. +16
  int arow = t >> 1, acol = (t & 1) * 16;
  const float* aF = X + (size_t)(row0 + arow) * DIN + acol;
  short* aW = &Al[arow * 32 + acol];

  // B: async global->LDS (linear [128][32] row-major)
  const short* bG = Bt + (size_t)(col0 + wid * 16 + (lane >> 2)) * DIN + (lane & 3) * 8;
  short* bL0 = &Bl[wid * 512];
  short* bL1 = &Bl[(4 + wid) * 512];

  const short* aR = &Al[(wr * 64 + lrow) * 32 + lhi * 8];
  const short* bR = &Bl[(wc * 64 + lrow) * 32 + lhi * 8];

  f32x4 acc[4][4] = {};

  for (int kk = 0; kk < DIN; kk += 32) {
    gload_lds16(bG + kk, bL0);
    gload_lds16(bG + 64 * DIN + kk, bL1);
    float4 x0 = *(const float4*)(aF + kk);
    float4 x1 = *(const float4*)(aF + kk + 4);
    float4 x2 = *(const float4*)(aF + kk + 8);
    float4 x3 = *(const float4*)(aF + kk + 12);
    bf16x8 v0, v1;
    v0[0] = f2bf(x0.x); v0[1] = f2bf(x0.y); v0[2] = f2bf(x0.z); v0[3] = f2bf(x0.w);
    v0[4] = f2bf(x1.x); v0[5] = f2bf(x1.y); v0[6] = f2bf(x1.z); v0[7] = f2bf(x1.w);
    v1[0] = f2bf(x2.x); v1[1] = f2bf(x2.y); v1[2] = f2bf(x2.z); v1[3] = f2bf(x2.w);
    v1[4] = f2bf(x3.x); v1[5] = f2bf(x3.y); v1[6] = f2bf(x3.z); v1[7] = f2bf(x3.w);
    *(bf16x8*)aW = v0;
    *(bf16x8*)(aW + 8) = v1;
    __syncthreads();
    bf16x8 af[4], bfv[4];
#pragma unroll
    for (int m = 0; m < 4; ++m) af[m] = *(const bf16x8*)(aR + m * 512);
#pragma unroll
    for (int n = 0; n < 4; ++n) bfv[n] = *(const bf16x8*)(bR + n * 512);
#pragma unroll
    for (int m = 0; m < 4; ++m)
#pragma unroll
      for (int n = 0; n < 4; ++n)
        acc[m][n] = __builtin_amdgcn_mfma_f32_16x16x32_bf16(af[m], bfv[n], acc[m][n], 0, 0, 0);
    __syncthreads();
  }

#pragma unroll
  for (int m = 0; m < 4; ++m) {
#pragma unroll
    for (int n = 0; n < 4; ++n) {
      int c = col0 + wc * 64 + n * 16 + lrow;
      int h = c >> 6, hc = c & 63;
      float bval = bias[c];
#pragma unroll
      for (int i = 0; i < 4; ++i) {
        int r = row0 + wr * 64 + m * 16 + lhi * 4 + i;
        int b = r >> 11, s = r & 2047;
        float val = acc[m][n][i] + bval;
        if (z == 2) vt[((size_t)(b * NH + h) * HD + hc) * SEQ + s] = f2bf(val);
        else {
          short* o = z == 0 ? qb : kb;
          o[((size_t)(b * NH + h) * SEQ + s) * HD + hc] = f2bf(val);
        }
      }
    }
  }
}

// flash attention: 64 q-rows per block (4 waves x 16), KV tiles of 64
__global__ __launch_bounds__(256) void attn_kernel(
    const short* __restrict__ qb, const short* __restrict__ kb,
    const short* __restrict__ vt, short* __restrict__ ob) {
  int qt = blockIdx.x, h = blockIdx.y, b = blockIdx.z;
  int t = threadIdx.x;
  int wid = t >> 6, lane = t & 63, lrow = lane & 15, lhi = lane >> 4;
  __shared__ __align__(16) short kl[64][72];
  __shared__ __align__(16) short vl[64][72];
  __shared__ __align__(16) short pl[64][72];

  const float SCL = 0.18033688011112042f;  // 0.125 * log2(e)

  size_t bh = (size_t)(b * NH + h);
  const short* qbase = qb + (bh * SEQ + qt * 64) * HD;
  bf16x8 aq0 = *(const bf16x8*)(qbase + (wid * 16 + lrow) * HD + lhi * 8);
  bf16x8 aq1 = *(const bf16x8*)(qbase + (wid * 16 + lrow) * HD + 32 + lhi * 8);

  const short* kbase = kb + bh * (size_t)SEQ * HD;
  const short* vbase = vt + bh * (size_t)HD * SEQ;

  f32x4 oacc[4] = {};
  float mrun[4], lrun[4];
#pragma unroll
  for (int i = 0; i < 4; ++i) { mrun[i] = -1e30f; lrun[i] = 0.f; }

  int sr = t >> 2, sc0 = (t & 3) * 16;
  for (int t0 = 0; t0 < SEQ; t0 += 64) {
    const bf16x8* ks = (const bf16x8*)(kbase + (size_t)(t0 + sr) * HD + sc0);
    *(bf16x8*)&kl[sr][sc0] = ks[0];
    *(bf16x8*)&kl[sr][sc0 + 8] = ks[1];
    const bf16x8* vs = (const bf16x8*)(vbase + (size_t)sr * SEQ + t0 + sc0);
    *(bf16x8*)&vl[sr][sc0] = vs[0];
    *(bf16x8*)&vl[sr][sc0 + 8] = vs[1];
    __syncthreads();

    f32x4 sc[4];
#pragma unroll
    for (int tt = 0; tt < 4; ++tt) {
      f32x4 z = {};
      bf16x8 b0 = *(bf16x8*)&kl[tt * 16 + lrow][lhi * 8];
      bf16x8 b1 = *(bf16x8*)&kl[tt * 16 + lrow][32 + lhi * 8];
      z = __builtin_amdgcn_mfma_f32_16x16x32_bf16(aq0, b0, z, 0, 0, 0);
      z = __builtin_amdgcn_mfma_f32_16x16x32_bf16(aq1, b1, z, 0, 0, 0);
      sc[tt] = z;
    }
#pragma unroll
    for (int i = 0; i < 4; ++i) {
      float s0 = sc[0][i] * SCL, s1 = sc[1][i] * SCL;
      float s2 = sc[2][i] * SCL, s3 = sc[3][i] * SCL;
      float mx = fmaxf(fmaxf(s0, s1), fmaxf(s2, s3));
      mx = fmaxf(mx, __shfl_xor(mx, 1));
      mx = fmaxf(mx, __shfl_xor(mx, 2));
      mx = fmaxf(mx, __shfl_xor(mx, 4));
      mx = fmaxf(mx, __shfl_xor(mx, 8));
      if (mx - mrun[i] > 8.f) {  // defer-max (T13): rescale only on large growth
        float corr = __builtin_amdgcn_exp2f(mrun[i] - mx);
        lrun[i] *= corr;
#pragma unroll
        for (int tt = 0; tt < 4; ++tt) oacc[tt][i] *= corr;
        mrun[i] = mx;
      }
      float m = mrun[i];
      float p0 = __builtin_amdgcn_exp2f(s0 - m), p1 = __builtin_amdgcn_exp2f(s1 - m);
      float p2 = __builtin_amdgcn_exp2f(s2 - m), p3 = __builtin_amdgcn_exp2f(s3 - m);
      float ps = p0 + p1 + p2 + p3;
      ps += __shfl_xor(ps, 1); ps += __shfl_xor(ps, 2);
      ps += __shfl_xor(ps, 4); ps += __shfl_xor(ps, 8);
      lrun[i] += ps;
      int rr = wid * 16 + lhi * 4 + i;
      pl[rr][0 + lrow] = f2bf(p0);
      pl[rr][16 + lrow] = f2bf(p1);
      pl[rr][32 + lrow] = f2bf(p2);
      pl[rr][48 + lrow] = f2bf(p3);
    }
    __syncthreads();
    bf16x8 ap0 = *(bf16x8*)&pl[wid * 16 + lrow][lhi * 8];
    bf16x8 ap1 = *(bf16x8*)&pl[wid * 16 + lrow][32 + lhi * 8];
#pragma unroll
    for (int tt = 0; tt < 4; ++tt) {
      bf16x8 b0 = *(bf16x8*)&vl[tt * 16 + lrow][lhi * 8];
      bf16x8 b1 = *(bf16x8*)&vl[tt * 16 + lrow][32 + lhi * 8];
      oacc[tt] = __builtin_amdgcn_mfma_f32_16x16x32_bf16(ap0, b0, oacc[tt], 0, 0, 0);
      oacc[tt] = __builtin_amdgcn_mfma_f32_16x16x32_bf16(ap1, b1, oacc[tt], 0, 0, 0);
    }
    __syncthreads();
  }
#pragma unroll
  for (int tt = 0; tt < 4; ++tt) {
    int col = tt * 16 + lrow;
#pragma unroll
    for (int i = 0; i < 4; ++i) {
      int rr = wid * 16 + lhi * 4 + i;
      float val = oacc[tt][i] / lrun[i];
      size_t addr = ((size_t)(b * SEQ + qt * 64 + rr)) * DIN + h * HD + col;
      ob[addr] = f2bf(val);
    }
  }
}

// out projection: 128x128-tile GEMM, fp32 out + bias
__global__ __launch_bounds__(256) void oproj_kernel(
    const short* __restrict__ ob, const short* __restrict__ wto,
    const float* __restrict__ bo, float* __restrict__ out) {
  int mt = blockIdx.x, nt = blockIdx.y;
  __shared__ __align__(16) short Al[128 * 32];
  __shared__ __align__(16) short Bl[128 * 32];
  int t = threadIdx.x, wid = t >> 6, lane = t & 63;
  int lrow = lane & 15, lhi = lane >> 4;
  int wr = wid >> 1, wc = wid & 1;
  int row0 = mt * 128, col0 = nt * 128;

  const short* aG = ob + (size_t)(row0 + wid * 16 + (lane >> 2)) * DIN + (lane & 3) * 8;
  const short* bG = wto + (size_t)(col0 + wid * 16 + (lane >> 2)) * DIN + (lane & 3) * 8;
  short* aL0 = &Al[wid * 512];
  short* aL1 = &Al[(4 + wid) * 512];
  short* bL0 = &Bl[wid * 512];
  short* bL1 = &Bl[(4 + wid) * 512];
  const short* aR = &Al[(wr * 64 + lrow) * 32 + lhi * 8];
  const short* bR = &Bl[(wc * 64 + lrow) * 32 + lhi * 8];

  f32x4 acc[4][4] = {};
  for (int kk = 0; kk < DIN; kk += 32) {
    gload_lds16(aG + kk, aL0);
    gload_lds16(aG + 64 * DIN + kk, aL1);
    gload_lds16(bG + kk, bL0);
    gload_lds16(bG + 64 * DIN + kk, bL1);
    __syncthreads();
    bf16x8 af[4], bfv[4];
#pragma unroll
    for (int m = 0; m < 4; ++m) af[m] = *(const bf16x8*)(aR + m * 512);
#pragma unroll
    for (int n = 0; n < 4; ++n) bfv[n] = *(const bf16x8*)(bR + n * 512);
#pragma unroll
    for (int m = 0; m < 4; ++m)
#pragma unroll
      for (int n = 0; n < 4; ++n)
        acc[m][n] = __builtin_amdgcn_mfma_f32_16x16x32_bf16(af[m], bfv[n], acc[m][n], 0, 0, 0);
    __syncthreads();
  }
#pragma unroll
  for (int m = 0; m < 4; ++m) {
#pragma unroll
    for (int n = 0; n < 4; ++n) {
      int c = col0 + wc * 64 + n * 16 + lrow;
      float bval = bo[c];
#pragma unroll
      for (int i = 0; i < 4; ++i) {
        int r = row0 + wr * 64 + m * 16 + lhi * 4 + i;
        out[(size_t)r * DIN + c] = acc[m][n][i] + bval;
      }
    }
  }
}

extern "C" void kernel_launch(void* const* d_in, const int* in_sizes, int n_in,
                              void* d_out, int out_size, void* d_ws, size_t ws_size,
                              hipStream_t stream) {
  const float* Q  = (const float*)d_in[0];
  const float* K  = (const float*)d_in[1];
  const float* V  = (const float*)d_in[2];
  const float* Wq = (const float*)d_in[3];
  const float* bq = (const float*)d_in[4];
  const float* Wk = (const float*)d_in[5];
  const float* bk = (const float*)d_in[6];
  const float* Wv = (const float*)d_in[7];
  const float* bv = (const float*)d_in[8];
  const float* Wo = (const float*)d_in[9];
  const float* bo = (const float*)d_in[10];
  float* out = (float*)d_out;

  short* ws = (short*)d_ws;
  const size_t NX = (size_t)NB * SEQ * DIN;        // 4194304 elems (8 MiB bf16)
  const size_t NW = (size_t)NH * HD * DIN;         // 1048576
  // total: 4*NX + 4*NW shorts = 40 MiB (same footprint as the passing R1 run)
  short* qbuf = ws;
  short* kbuf = qbuf + NX;
  short* vtb  = kbuf + NX;
  short* obuf = vtb + NX;
  short* wtq  = obuf + NX;   // [3][H][64][1024] combined
  short* wto  = wtq + 3 * NW;

  wt3_kernel<<<dim3(1, 16, 48), 256, 0, stream>>>(Wq, Wk, Wv, wtq);
  wt_kernel<<<dim3(16, 16, 1), 256, 0, stream>>>(Wo, wto, DIN, DIN);
  proj_kernel<<<dim3(32, 8, 3), 256, 0, stream>>>(Q, K, V, wtq, bq, bk, bv,
                                                  qbuf, kbuf, vtb);
  attn_kernel<<<dim3(32, 16, 2), 256, 0, stream>>>(qbuf, kbuf, vtb, obuf);
  oproj_kernel<<<dim3(32, 8), 256, 0, stream>>>(obuf, wto, bo, out);
}

// Round 4
// 312.138 us; speedup vs baseline: 1.1493x; 1.0057x over previous
//
#include <hip/hip_runtime.h>
#include <hip/hip_bf16.h>

#define DIN 1024
#define NH 16
#define HD 64
#define SEQ 2048
#define NB 2

typedef __attribute__((ext_vector_type(8))) short bf16x8;
typedef __attribute__((ext_vector_type(4))) float f32x4;

__device__ inline short f2bf(float f) {
  union { float f; unsigned u; } v; v.f = f;
  unsigned r = v.u + 0x7fff + ((v.u >> 16) & 1);
  return (short)(r >> 16);
}

__device__ __forceinline__ void gload_lds16(const void* g, void* l) {
  __builtin_amdgcn_global_load_lds(
      (const __attribute__((address_space(1))) unsigned*)g,
      (__attribute__((address_space(3))) unsigned*)l, 16, 0, 0);
}

// fp32 Q/K/V [4096][1024] -> bf16, vectorized 8/thread
__global__ __launch_bounds__(256) void cvt_kernel(
    const float* __restrict__ Q, const float* __restrict__ K, const float* __restrict__ V,
    short* __restrict__ xq, short* __restrict__ xk, short* __restrict__ xv) {
  int z = blockIdx.y;
  const float* src = z == 0 ? Q : (z == 1 ? K : V);
  short* dst = z == 0 ? xq : (z == 1 ? xk : xv);
  size_t e = ((size_t)blockIdx.x * 256 + threadIdx.x) * 8;
  float4 x0 = *(const float4*)(src + e);
  float4 x1 = *(const float4*)(src + e + 4);
  bf16x8 v;
  v[0] = f2bf(x0.x); v[1] = f2bf(x0.y); v[2] = f2bf(x0.z); v[3] = f2bf(x0.w);
  v[4] = f2bf(x1.x); v[5] = f2bf(x1.y); v[6] = f2bf(x1.z); v[7] = f2bf(x1.w);
  *(bf16x8*)(dst + e) = v;
}

// Wq/Wk/Wv [H][1024][64] fp32 -> Wt [3][H][64][1024] bf16 (transposed per head)
__global__ __launch_bounds__(256) void wt3_kernel(
    const float* __restrict__ Wq, const float* __restrict__ Wk, const float* __restrict__ Wv,
    short* __restrict__ out) {
  int zz = blockIdx.z; int which = zz >> 4, h = zz & 15;
  const float* in = (which == 0 ? Wq : (which == 1 ? Wk : Wv)) + (size_t)h * (DIN * HD);
  short* o = out + (size_t)which * (NH * HD * DIN) + (size_t)h * (HD * DIN);
  __shared__ float tile[64][65];
  int r0 = blockIdx.y * 64;
  int t = threadIdx.x;
  int r = t >> 2, cc = (t & 3) * 16;
#pragma unroll
  for (int j = 0; j < 16; ++j) tile[r][cc + j] = in[(size_t)(r0 + r) * HD + cc + j];
  __syncthreads();
  int c = t >> 2, rr = (t & 3) * 16;
#pragma unroll
  for (int j = 0; j < 16; ++j) o[(size_t)c * DIN + r0 + rr + j] = f2bf(tile[rr + j][c]);
}

// Wo [1024][1024] fp32 -> Wot [1024 n][1024 k] bf16
__global__ __launch_bounds__(256) void wt_kernel(const float* __restrict__ in,
                                                 short* __restrict__ out, int R, int C) {
  __shared__ float tile[64][65];
  int r0 = blockIdx.y * 64, c0 = blockIdx.x * 64;
  int t = threadIdx.x;
  int r = t >> 2, cc = (t & 3) * 16;
#pragma unroll
  for (int j = 0; j < 16; ++j) tile[r][cc + j] = in[(size_t)(r0 + r) * C + c0 + cc + j];
  __syncthreads();
  int c = t >> 2, rr = (t & 3) * 16;
#pragma unroll
  for (int j = 0; j < 16; ++j) out[(size_t)(c0 + c) * R + r0 + rr + j] = f2bf(tile[rr + j][c]);
}

#define QSCL 0.18033688011112042f  // 0.125 * log2(e), folded into q at proj time

// 128x128-tile GEMM (m97): A bf16 + B bf16 both via global_load_lds.
// q (pre-scaled by QSCL), k row-major [B,H,S,64]; v transposed [B,H,64,S].
__global__ __launch_bounds__(256) void proj_bf16_kernel(
    const short* __restrict__ xq, const short* __restrict__ xk, const short* __restrict__ xv,
    const short* __restrict__ wt,
    const float* __restrict__ bq, const float* __restrict__ bk, const float* __restrict__ bv,
    short* __restrict__ qb, short* __restrict__ kb, short* __restrict__ vt) {
  int mt = blockIdx.x, nt = blockIdx.y, z = blockIdx.z;
  const short* A = z == 0 ? xq : (z == 1 ? xk : xv);
  const short* Bt = wt + (size_t)z * (DIN * DIN);
  const float* bias = z == 0 ? bq : (z == 1 ? bk : bv);

  __shared__ __align__(16) short Al[128 * 32];
  __shared__ __align__(16) short Bl[128 * 32];

  int t = threadIdx.x, wid = t >> 6, lane = t & 63;
  int lrow = lane & 15, lhi = lane >> 4;
  int wr = wid >> 1, wc = wid & 1;
  int row0 = mt * 128, col0 = nt * 128;

  const short* aG = A + (size_t)(row0 + wid * 16 + (lane >> 2)) * DIN + (lane & 3) * 8;
  const short* bG = Bt + (size_t)(col0 + wid * 16 + (lane >> 2)) * DIN + (lane & 3) * 8;
  short* aL0 = &Al[wid * 512];
  short* aL1 = &Al[(4 + wid) * 512];
  short* bL0 = &Bl[wid * 512];
  short* bL1 = &Bl[(4 + wid) * 512];
  const short* aR = &Al[(wr * 64 + lrow) * 32 + lhi * 8];
  const short* bR = &Bl[(wc * 64 + lrow) * 32 + lhi * 8];

  f32x4 acc[4][4] = {};
  for (int kk = 0; kk < DIN; kk += 32) {
    gload_lds16(aG + kk, aL0);
    gload_lds16(aG + 64 * DIN + kk, aL1);
    gload_lds16(bG + kk, bL0);
    gload_lds16(bG + 64 * DIN + kk, bL1);
    __syncthreads();
    bf16x8 af[4], bfv[4];
#pragma unroll
    for (int m = 0; m < 4; ++m) af[m] = *(const bf16x8*)(aR + m * 512);
#pragma unroll
    for (int n = 0; n < 4; ++n) bfv[n] = *(const bf16x8*)(bR + n * 512);
#pragma unroll
    for (int m = 0; m < 4; ++m)
#pragma unroll
      for (int n = 0; n < 4; ++n)
        acc[m][n] = __builtin_amdgcn_mfma_f32_16x16x32_bf16(af[m], bfv[n], acc[m][n], 0, 0, 0);
    __syncthreads();
  }

#pragma unroll
  for (int m = 0; m < 4; ++m) {
#pragma unroll
    for (int n = 0; n < 4; ++n) {
      int c = col0 + wc * 64 + n * 16 + lrow;
      int h = c >> 6, hc = c & 63;
      float bval = bias[c];
#pragma unroll
      for (int i = 0; i < 4; ++i) {
        int r = row0 + wr * 64 + m * 16 + lhi * 4 + i;
        int b = r >> 11, s = r & 2047;
        float val = acc[m][n][i] + bval;
        if (z == 0) val *= QSCL;
        if (z == 2) vt[((size_t)(b * NH + h) * HD + hc) * SEQ + s] = f2bf(val);
        else {
          short* o = z == 0 ? qb : kb;
          o[((size_t)(b * NH + h) * SEQ + s) * HD + hc] = f2bf(val);
        }
      }
    }
  }
}

// fallback (40 MiB ws): fp32 A reg-staged + cvt in-loop
__global__ __launch_bounds__(256) void proj_f32_kernel(
    const float* __restrict__ Q, const float* __restrict__ K, const float* __restrict__ V,
    const short* __restrict__ wt,
    const float* __restrict__ bq, const float* __restrict__ bk, const float* __restrict__ bv,
    short* __restrict__ qb, short* __restrict__ kb, short* __restrict__ vt) {
  int mt = blockIdx.x, nt = blockIdx.y, z = blockIdx.z;
  const float* X = z == 0 ? Q : (z == 1 ? K : V);
  const short* Bt = wt + (size_t)z * (DIN * DIN);
  const float* bias = z == 0 ? bq : (z == 1 ? bk : bv);

  __shared__ __align__(16) short Al[128 * 32];
  __shared__ __align__(16) short Bl[128 * 32];

  int t = threadIdx.x, wid = t >> 6, lane = t & 63;
  int lrow = lane & 15, lhi = lane >> 4;
  int wr = wid >> 1, wc = wid & 1;
  int row0 = mt * 128, col0 = nt * 128;

  int arow = t >> 1, acol = (t & 1) * 16;
  const float* aF = X + (size_t)(row0 + arow) * DIN + acol;
  short* aW = &Al[arow * 32 + acol];

  const short* bG = Bt + (size_t)(col0 + wid * 16 + (lane >> 2)) * DIN + (lane & 3) * 8;
  short* bL0 = &Bl[wid * 512];
  short* bL1 = &Bl[(4 + wid) * 512];

  const short* aR = &Al[(wr * 64 + lrow) * 32 + lhi * 8];
  const short* bR = &Bl[(wc * 64 + lrow) * 32 + lhi * 8];

  f32x4 acc[4][4] = {};
  for (int kk = 0; kk < DIN; kk += 32) {
    gload_lds16(bG + kk, bL0);
    gload_lds16(bG + 64 * DIN + kk, bL1);
    float4 x0 = *(const float4*)(aF + kk);
    float4 x1 = *(const float4*)(aF + kk + 4);
    float4 x2 = *(const float4*)(aF + kk + 8);
    float4 x3 = *(const float4*)(aF + kk + 12);
    bf16x8 v0, v1;
    v0[0] = f2bf(x0.x); v0[1] = f2bf(x0.y); v0[2] = f2bf(x0.z); v0[3] = f2bf(x0.w);
    v0[4] = f2bf(x1.x); v0[5] = f2bf(x1.y); v0[6] = f2bf(x1.z); v0[7] = f2bf(x1.w);
    v1[0] = f2bf(x2.x); v1[1] = f2bf(x2.y); v1[2] = f2bf(x2.z); v1[3] = f2bf(x2.w);
    v1[4] = f2bf(x3.x); v1[5] = f2bf(x3.y); v1[6] = f2bf(x3.z); v1[7] = f2bf(x3.w);
    *(bf16x8*)aW = v0;
    *(bf16x8*)(aW + 8) = v1;
    __syncthreads();
    bf16x8 af[4], bfv[4];
#pragma unroll
    for (int m = 0; m < 4; ++m) af[m] = *(const bf16x8*)(aR + m * 512);
#pragma unroll
    for (int n = 0; n < 4; ++n) bfv[n] = *(const bf16x8*)(bR + n * 512);
#pragma unroll
    for (int m = 0; m < 4; ++m)
#pragma unroll
      for (int n = 0; n < 4; ++n)
        acc[m][n] = __builtin_amdgcn_mfma_f32_16x16x32_bf16(af[m], bfv[n], acc[m][n], 0, 0, 0);
    __syncthreads();
  }
#pragma unroll
  for (int m = 0; m < 4; ++m) {
#pragma unroll
    for (int n = 0; n < 4; ++n) {
      int c = col0 + wc * 64 + n * 16 + lrow;
      int h = c >> 6, hc = c & 63;
      float bval = bias[c];
#pragma unroll
      for (int i = 0; i < 4; ++i) {
        int r = row0 + wr * 64 + m * 16 + lhi * 4 + i;
        int b = r >> 11, s = r & 2047;
        float val = acc[m][n][i] + bval;
        if (z == 0) val *= QSCL;
        if (z == 2) vt[((size_t)(b * NH + h) * HD + hc) * SEQ + s] = f2bf(val);
        else {
          short* o = z == 0 ? qb : kb;
          o[((size_t)(b * NH + h) * SEQ + s) * HD + hc] = f2bf(val);
        }
      }
    }
  }
}

// flash attention: 64 q-rows/block (4 waves x 16), KV tiles of 64.
// XOR-swizzled LDS (T2), K/V double-buffer, 1 barrier/tile, async-stage (T14).
__global__ __launch_bounds__(256) void attn_kernel(
    const short* __restrict__ qb, const short* __restrict__ kb,
    const short* __restrict__ vt, short* __restrict__ ob) {
  int qt = blockIdx.x, h = blockIdx.y, b = blockIdx.z;
  int t = threadIdx.x;
  int wid = t >> 6, lane = t & 63, lrow = lane & 15, lhi = lane >> 4;
  __shared__ __align__(16) short kl[2][64][64];
  __shared__ __align__(16) short vl[2][64][64];
  __shared__ __align__(16) short pl[64][64];

  size_t bh = (size_t)(b * NH + h);
  const short* qbase = qb + (bh * SEQ + qt * 64) * HD;
  bf16x8 aq0 = *(const bf16x8*)(qbase + (wid * 16 + lrow) * HD + lhi * 8);
  bf16x8 aq1 = *(const bf16x8*)(qbase + (wid * 16 + lrow) * HD + 32 + lhi * 8);

  const short* kbase = kb + bh * (size_t)SEQ * HD;
  const short* vbase = vt + bh * (size_t)HD * SEQ;

  f32x4 oacc[4] = {};
  float mrun[4], lrun[4];
#pragma unroll
  for (int i = 0; i < 4; ++i) { mrun[i] = -1e30f; lrun[i] = 0.f; }

  // stage-side swizzle: thread stages row sr, 16-short chunk at sc0
  int sr = t >> 2, sc0 = (t & 3) * 16;
  int sw = (sr & 7) << 3;
  int c0 = sc0 ^ sw, c1 = (sc0 + 8) ^ sw;
  // read-side swizzle: row = tt*16+lrow -> row&7 == lrow&7
  int rs = (lrow & 7) << 3;
  int rc0 = (lhi * 8) ^ rs, rc1 = (32 + lhi * 8) ^ rs;
  int ps = 0;  // pl row swizzle computed per-i below

  // prologue: tile 0
  {
    const bf16x8* ks = (const bf16x8*)(kbase + (size_t)sr * HD + sc0);
    *(bf16x8*)&kl[0][sr][c0] = ks[0];
    *(bf16x8*)&kl[0][sr][c1] = ks[1];
    const bf16x8* vs = (const bf16x8*)(vbase + (size_t)sr * SEQ + sc0);
    *(bf16x8*)&vl[0][sr][c0] = vs[0];
    *(bf16x8*)&vl[0][sr][c1] = vs[1];
  }
  int cur = 0;
  for (int t0 = 0; t0 < SEQ; t0 += 64) {
    __syncthreads();  // staged writes from prev iter visible; bufB free
    bool more = (t0 + 64) < SEQ;
    bf16x8 nk0, nk1, nv0, nv1;
    if (more) {  // issue next-tile loads early; consumed after softmax
      const bf16x8* ks = (const bf16x8*)(kbase + (size_t)(t0 + 64 + sr) * HD + sc0);
      nk0 = ks[0]; nk1 = ks[1];
      const bf16x8* vs = (const bf16x8*)(vbase + (size_t)sr * SEQ + t0 + 64 + sc0);
      nv0 = vs[0]; nv1 = vs[1];
    }
    f32x4 sc4[4];
#pragma unroll
    for (int tt = 0; tt < 4; ++tt) {
      f32x4 z = {};
      bf16x8 b0 = *(bf16x8*)&kl[cur][tt * 16 + lrow][rc0];
      bf16x8 b1 = *(bf16x8*)&kl[cur][tt * 16 + lrow][rc1];
      z = __builtin_amdgcn_mfma_f32_16x16x32_bf16(aq0, b0, z, 0, 0, 0);
      z = __builtin_amdgcn_mfma_f32_16x16x32_bf16(aq1, b1, z, 0, 0, 0);
      sc4[tt] = z;
    }
#pragma unroll
    for (int i = 0; i < 4; ++i) {
      float s0 = sc4[0][i], s1 = sc4[1][i], s2 = sc4[2][i], s3 = sc4[3][i];
      float mx = fmaxf(fmaxf(s0, s1), fmaxf(s2, s3));
      mx = fmaxf(mx, __shfl_xor(mx, 1));
      mx = fmaxf(mx, __shfl_xor(mx, 2));
      mx = fmaxf(mx, __shfl_xor(mx, 4));
      mx = fmaxf(mx, __shfl_xor(mx, 8));
      if (mx - mrun[i] > 8.f) {  // defer-max (T13)
        float corr = __builtin_amdgcn_exp2f(mrun[i] - mx);
        lrun[i] *= corr;
#pragma unroll
        for (int tt = 0; tt < 4; ++tt) oacc[tt][i] *= corr;
        mrun[i] = mx;
      }
      float m = mrun[i];
      float p0 = __builtin_amdgcn_exp2f(s0 - m), p1 = __builtin_amdgcn_exp2f(s1 - m);
      float p2 = __builtin_amdgcn_exp2f(s2 - m), p3 = __builtin_amdgcn_exp2f(s3 - m);
      float psum = p0 + p1 + p2 + p3;
      psum += __shfl_xor(psum, 1); psum += __shfl_xor(psum, 2);
      psum += __shfl_xor(psum, 4); psum += __shfl_xor(psum, 8);
      lrun[i] += psum;
      int rr = wid * 16 + lhi * 4 + i;
      int rw = (rr & 7) << 3;
      pl[rr][(0 + lrow) ^ rw] = f2bf(p0);
      pl[rr][(16 + lrow) ^ rw] = f2bf(p1);
      pl[rr][(32 + lrow) ^ rw] = f2bf(p2);
      pl[rr][(48 + lrow) ^ rw] = f2bf(p3);
    }
    if (more) {  // write next tile to the other buffer (no barrier needed)
      *(bf16x8*)&kl[cur ^ 1][sr][c0] = nk0;
      *(bf16x8*)&kl[cur ^ 1][sr][c1] = nk1;
      *(bf16x8*)&vl[cur ^ 1][sr][c0] = nv0;
      *(bf16x8*)&vl[cur ^ 1][sr][c1] = nv1;
    }
    // pl is wave-private (rows wid*16..+15): lgkmcnt ordering suffices, no barrier
    bf16x8 ap0 = *(bf16x8*)&pl[wid * 16 + lrow][rc0];
    bf16x8 ap1 = *(bf16x8*)&pl[wid * 16 + lrow][rc1];
#pragma unroll
    for (int tt = 0; tt < 4; ++tt) {
      bf16x8 b0 = *(bf16x8*)&vl[cur][tt * 16 + lrow][rc0];
      bf16x8 b1 = *(bf16x8*)&vl[cur][tt * 16 + lrow][rc1];
      oacc[tt] = __builtin_amdgcn_mfma_f32_16x16x32_bf16(ap0, b0, oacc[tt], 0, 0, 0);
      oacc[tt] = __builtin_amdgcn_mfma_f32_16x16x32_bf16(ap1, b1, oacc[tt], 0, 0, 0);
    }
    cur ^= 1;
  }
#pragma unroll
  for (int tt = 0; tt < 4; ++tt) {
    int col = tt * 16 + lrow;
#pragma unroll
    for (int i = 0; i < 4; ++i) {
      int rr = wid * 16 + lhi * 4 + i;
      float val = oacc[tt][i] / lrun[i];
      size_t addr = ((size_t)(b * SEQ + qt * 64 + rr)) * DIN + h * HD + col;
      ob[addr] = f2bf(val);
    }
  }
}

// out projection: 128x128-tile GEMM, fp32 out + bias
__global__ __launch_bounds__(256) void oproj_kernel(
    const short* __restrict__ ob, const short* __restrict__ wto,
    const float* __restrict__ bo, float* __restrict__ out) {
  int mt = blockIdx.x, nt = blockIdx.y;
  __shared__ __align__(16) short Al[128 * 32];
  __shared__ __align__(16) short Bl[128 * 32];
  int t = threadIdx.x, wid = t >> 6, lane = t & 63;
  int lrow = lane & 15, lhi = lane >> 4;
  int wr = wid >> 1, wc = wid & 1;
  int row0 = mt * 128, col0 = nt * 128;

  const short* aG = ob + (size_t)(row0 + wid * 16 + (lane >> 2)) * DIN + (lane & 3) * 8;
  const short* bG = wto + (size_t)(col0 + wid * 16 + (lane >> 2)) * DIN + (lane & 3) * 8;
  short* aL0 = &Al[wid * 512];
  short* aL1 = &Al[(4 + wid) * 512];
  short* bL0 = &Bl[wid * 512];
  short* bL1 = &Bl[(4 + wid) * 512];
  const short* aR = &Al[(wr * 64 + lrow) * 32 + lhi * 8];
  const short* bR = &Bl[(wc * 64 + lrow) * 32 + lhi * 8];

  f32x4 acc[4][4] = {};
  for (int kk = 0; kk < DIN; kk += 32) {
    gload_lds16(aG + kk, aL0);
    gload_lds16(aG + 64 * DIN + kk, aL1);
    gload_lds16(bG + kk, bL0);
    gload_lds16(bG + 64 * DIN + kk, bL1);
    __syncthreads();
    bf16x8 af[4], bfv[4];
#pragma unroll
    for (int m = 0; m < 4; ++m) af[m] = *(const bf16x8*)(aR + m * 512);
#pragma unroll
    for (int n = 0; n < 4; ++n) bfv[n] = *(const bf16x8*)(bR + n * 512);
#pragma unroll
    for (int m = 0; m < 4; ++m)
#pragma unroll
      for (int n = 0; n < 4; ++n)
        acc[m][n] = __builtin_amdgcn_mfma_f32_16x16x32_bf16(af[m], bfv[n], acc[m][n], 0, 0, 0);
    __syncthreads();
  }
#pragma unroll
  for (int m = 0; m < 4; ++m) {
#pragma unroll
    for (int n = 0; n < 4; ++n) {
      int c = col0 + wc * 64 + n * 16 + lrow;
      float bval = bo[c];
#pragma unroll
      for (int i = 0; i < 4; ++i) {
        int r = row0 + wr * 64 + m * 16 + lhi * 4 + i;
        out[(size_t)r * DIN + c] = acc[m][n][i] + bval;
      }
    }
  }
}

extern "C" void kernel_launch(void* const* d_in, const int* in_sizes, int n_in,
                              void* d_out, int out_size, void* d_ws, size_t ws_size,
                              hipStream_t stream) {
  const float* Q  = (const float*)d_in[0];
  const float* K  = (const float*)d_in[1];
  const float* V  = (const float*)d_in[2];
  const float* Wq = (const float*)d_in[3];
  const float* bq = (const float*)d_in[4];
  const float* Wk = (const float*)d_in[5];
  const float* bk = (const float*)d_in[6];
  const float* Wv = (const float*)d_in[7];
  const float* bv = (const float*)d_in[8];
  const float* Wo = (const float*)d_in[9];
  const float* bo = (const float*)d_in[10];
  float* out = (float*)d_out;

  short* ws = (short*)d_ws;
  const size_t NX = (size_t)NB * SEQ * DIN;        // 4194304 elems (8 MiB bf16)
  const size_t NW = (size_t)NH * HD * DIN;         // 1048576
  // shared base layout (40 MiB, R1/R3-proven):
  short* qbuf = ws;
  short* kbuf = qbuf + NX;
  short* vtb  = kbuf + NX;
  short* obuf = vtb + NX;
  short* wtq  = obuf + NX;   // [3][H][64][1024] combined
  short* wto  = wtq + 3 * NW;
  // big path extras (needs 64 MiB total):
  short* xq = wto + NW;
  short* xk = xq + NX;
  short* xv = xk + NX;
  const size_t need_big = (7 * NX + 4 * NW) * sizeof(short);  // 64 MiB

  wt3_kernel<<<dim3(1, 16, 48), 256, 0, stream>>>(Wq, Wk, Wv, wtq);
  wt_kernel<<<dim3(16, 16, 1), 256, 0, stream>>>(Wo, wto, DIN, DIN);
  if (ws_size >= need_big) {
    cvt_kernel<<<dim3(2048, 3), 256, 0, stream>>>(Q, K, V, xq, xk, xv);
    proj_bf16_kernel<<<dim3(32, 8, 3), 256, 0, stream>>>(xq, xk, xv, wtq, bq, bk, bv,
                                                         qbuf, kbuf, vtb);
  } else {
    proj_f32_kernel<<<dim3(32, 8, 3), 256, 0, stream>>>(Q, K, V, wtq, bq, bk, bv,
                                                        qbuf, kbuf, vtb);
  }
  attn_kernel<<<dim3(32, 16, 2), 256, 0, stream>>>(qbuf, kbuf, vtb, obuf);
  oproj_kernel<<<dim3(32, 8), 256, 0, stream>>>(obuf, wto, bo, out);
}

// Round 5
// 249.979 us; speedup vs baseline: 1.4350x; 1.2487x over previous
//
#include <hip/hip_runtime.h>
#include <hip/hip_bf16.h>

#define DIN 1024
#define NH 16
#define HD 64
#define SEQ 2048
#define NB 2

typedef __attribute__((ext_vector_type(8))) short bf16x8;
typedef __attribute__((ext_vector_type(4))) float f32x4;
typedef __attribute__((ext_vector_type(16))) float f32x16;

__device__ inline short f2bf(float f) {
  union { float f; unsigned u; } v; v.f = f;
  unsigned r = v.u + 0x7fff + ((v.u >> 16) & 1);
  return (short)(r >> 16);
}

__device__ inline unsigned pk2(float lo, float hi) {
  return (unsigned)(unsigned short)f2bf(lo) | ((unsigned)(unsigned short)f2bf(hi) << 16);
}

union U8 { unsigned u[4]; bf16x8 v; };
__device__ inline bf16x8 mkfrag(unsigned a, unsigned b, unsigned c, unsigned d) {
  U8 x; x.u[0] = a; x.u[1] = b; x.u[2] = c; x.u[3] = d; return x.v;
}

__device__ __forceinline__ void gload_lds16(const void* g, void* l) {
  __builtin_amdgcn_global_load_lds(
      (const __attribute__((address_space(1))) unsigned*)g,
      (__attribute__((address_space(3))) unsigned*)l, 16, 0, 0);
}

// fp32 Q/K/V [4096][1024] -> bf16, vectorized 8/thread
__global__ __launch_bounds__(256) void cvt_kernel(
    const float* __restrict__ Q, const float* __restrict__ K, const float* __restrict__ V,
    short* __restrict__ xq, short* __restrict__ xk, short* __restrict__ xv) {
  int z = blockIdx.y;
  const float* src = z == 0 ? Q : (z == 1 ? K : V);
  short* dst = z == 0 ? xq : (z == 1 ? xk : xv);
  size_t e = ((size_t)blockIdx.x * 256 + threadIdx.x) * 8;
  float4 x0 = *(const float4*)(src + e);
  float4 x1 = *(const float4*)(src + e + 4);
  bf16x8 v;
  v[0] = f2bf(x0.x); v[1] = f2bf(x0.y); v[2] = f2bf(x0.z); v[3] = f2bf(x0.w);
  v[4] = f2bf(x1.x); v[5] = f2bf(x1.y); v[6] = f2bf(x1.z); v[7] = f2bf(x1.w);
  *(bf16x8*)(dst + e) = v;
}

// Wq/Wk/Wv [H][1024][64] fp32 -> Wt [3][H][64][1024] bf16 (transposed per head)
__global__ __launch_bounds__(256) void wt3_kernel(
    const float* __restrict__ Wq, const float* __restrict__ Wk, const float* __restrict__ Wv,
    short* __restrict__ out) {
  int zz = blockIdx.z; int which = zz >> 4, h = zz & 15;
  const float* in = (which == 0 ? Wq : (which == 1 ? Wk : Wv)) + (size_t)h * (DIN * HD);
  short* o = out + (size_t)which * (NH * HD * DIN) + (size_t)h * (HD * DIN);
  __shared__ float tile[64][65];
  int r0 = blockIdx.y * 64;
  int t = threadIdx.x;
  int r = t >> 2, cc = (t & 3) * 16;
#pragma unroll
  for (int j = 0; j < 16; ++j) tile[r][cc + j] = in[(size_t)(r0 + r) * HD + cc + j];
  __syncthreads();
  int c = t >> 2, rr = (t & 3) * 16;
#pragma unroll
  for (int j = 0; j < 16; ++j) o[(size_t)c * DIN + r0 + rr + j] = f2bf(tile[rr + j][c]);
}

// Wo [1024][1024] fp32 -> Wot [1024 n][1024 k] bf16
__global__ __launch_bounds__(256) void wt_kernel(const float* __restrict__ in,
                                                 short* __restrict__ out, int R, int C) {
  __shared__ float tile[64][65];
  int r0 = blockIdx.y * 64, c0 = blockIdx.x * 64;
  int t = threadIdx.x;
  int r = t >> 2, cc = (t & 3) * 16;
#pragma unroll
  for (int j = 0; j < 16; ++j) tile[r][cc + j] = in[(size_t)(r0 + r) * C + c0 + cc + j];
  __syncthreads();
  int c = t >> 2, rr = (t & 3) * 16;
#pragma unroll
  for (int j = 0; j < 16; ++j) out[(size_t)(c0 + c) * R + r0 + rr + j] = f2bf(tile[rr + j][c]);
}

#define QSCL 0.18033688011112042f  // 0.125 * log2(e), folded into q at proj time

// 128x128-tile GEMM (m97): A bf16 + B bf16 both via global_load_lds.
__global__ __launch_bounds__(256) void proj_bf16_kernel(
    const short* __restrict__ xq, const short* __restrict__ xk, const short* __restrict__ xv,
    const short* __restrict__ wt,
    const float* __restrict__ bq, const float* __restrict__ bk, const float* __restrict__ bv,
    short* __restrict__ qb, short* __restrict__ kb, short* __restrict__ vt) {
  int mt = blockIdx.x, nt = blockIdx.y, z = blockIdx.z;
  const short* A = z == 0 ? xq : (z == 1 ? xk : xv);
  const short* Bt = wt + (size_t)z * (DIN * DIN);
  const float* bias = z == 0 ? bq : (z == 1 ? bk : bv);

  __shared__ __align__(16) short Al[128 * 32];
  __shared__ __align__(16) short Bl[128 * 32];

  int t = threadIdx.x, wid = t >> 6, lane = t & 63;
  int lrow = lane & 15, lhi = lane >> 4;
  int wr = wid >> 1, wc = wid & 1;
  int row0 = mt * 128, col0 = nt * 128;

  const short* aG = A + (size_t)(row0 + wid * 16 + (lane >> 2)) * DIN + (lane & 3) * 8;
  const short* bG = Bt + (size_t)(col0 + wid * 16 + (lane >> 2)) * DIN + (lane & 3) * 8;
  short* aL0 = &Al[wid * 512];
  short* aL1 = &Al[(4 + wid) * 512];
  short* bL0 = &Bl[wid * 512];
  short* bL1 = &Bl[(4 + wid) * 512];
  const short* aR = &Al[(wr * 64 + lrow) * 32 + lhi * 8];
  const short* bR = &Bl[(wc * 64 + lrow) * 32 + lhi * 8];

  f32x4 acc[4][4] = {};
  for (int kk = 0; kk < DIN; kk += 32) {
    gload_lds16(aG + kk, aL0);
    gload_lds16(aG + 64 * DIN + kk, aL1);
    gload_lds16(bG + kk, bL0);
    gload_lds16(bG + 64 * DIN + kk, bL1);
    __syncthreads();
    bf16x8 af[4], bfv[4];
#pragma unroll
    for (int m = 0; m < 4; ++m) af[m] = *(const bf16x8*)(aR + m * 512);
#pragma unroll
    for (int n = 0; n < 4; ++n) bfv[n] = *(const bf16x8*)(bR + n * 512);
#pragma unroll
    for (int m = 0; m < 4; ++m)
#pragma unroll
      for (int n = 0; n < 4; ++n)
        acc[m][n] = __builtin_amdgcn_mfma_f32_16x16x32_bf16(af[m], bfv[n], acc[m][n], 0, 0, 0);
    __syncthreads();
  }

#pragma unroll
  for (int m = 0; m < 4; ++m) {
#pragma unroll
    for (int n = 0; n < 4; ++n) {
      int c = col0 + wc * 64 + n * 16 + lrow;
      int h = c >> 6, hc = c & 63;
      float bval = bias[c];
#pragma unroll
      for (int i = 0; i < 4; ++i) {
        int r = row0 + wr * 64 + m * 16 + lhi * 4 + i;
        int b = r >> 11, s = r & 2047;
        float val = acc[m][n][i] + bval;
        if (z == 0) val *= QSCL;
        if (z == 2) vt[((size_t)(b * NH + h) * HD + hc) * SEQ + s] = f2bf(val);
        else {
          short* o = z == 0 ? qb : kb;
          o[((size_t)(b * NH + h) * SEQ + s) * HD + hc] = f2bf(val);
        }
      }
    }
  }
}

// fallback (40 MiB ws): fp32 A reg-staged + cvt in-loop
__global__ __launch_bounds__(256) void proj_f32_kernel(
    const float* __restrict__ Q, const float* __restrict__ K, const float* __restrict__ V,
    const short* __restrict__ wt,
    const float* __restrict__ bq, const float* __restrict__ bk, const float* __restrict__ bv,
    short* __restrict__ qb, short* __restrict__ kb, short* __restrict__ vt) {
  int mt = blockIdx.x, nt = blockIdx.y, z = blockIdx.z;
  const float* X = z == 0 ? Q : (z == 1 ? K : V);
  const short* Bt = wt + (size_t)z * (DIN * DIN);
  const float* bias = z == 0 ? bq : (z == 1 ? bk : bv);

  __shared__ __align__(16) short Al[128 * 32];
  __shared__ __align__(16) short Bl[128 * 32];

  int t = threadIdx.x, wid = t >> 6, lane = t & 63;
  int lrow = lane & 15, lhi = lane >> 4;
  int wr = wid >> 1, wc = wid & 1;
  int row0 = mt * 128, col0 = nt * 128;

  int arow = t >> 1, acol = (t & 1) * 16;
  const float* aF = X + (size_t)(row0 + arow) * DIN + acol;
  short* aW = &Al[arow * 32 + acol];

  const short* bG = Bt + (size_t)(col0 + wid * 16 + (lane >> 2)) * DIN + (lane & 3) * 8;
  short* bL0 = &Bl[wid * 512];
  short* bL1 = &Bl[(4 + wid) * 512];

  const short* aR = &Al[(wr * 64 + lrow) * 32 + lhi * 8];
  const short* bR = &Bl[(wc * 64 + lrow) * 32 + lhi * 8];

  f32x4 acc[4][4] = {};
  for (int kk = 0; kk < DIN; kk += 32) {
    gload_lds16(bG + kk, bL0);
    gload_lds16(bG + 64 * DIN + kk, bL1);
    float4 x0 = *(const float4*)(aF + kk);
    float4 x1 = *(const float4*)(aF + kk + 4);
    float4 x2 = *(const float4*)(aF + kk + 8);
    float4 x3 = *(const float4*)(aF + kk + 12);
    bf16x8 v0, v1;
    v0[0] = f2bf(x0.x); v0[1] = f2bf(x0.y); v0[2] = f2bf(x0.z); v0[3] = f2bf(x0.w);
    v0[4] = f2bf(x1.x); v0[5] = f2bf(x1.y); v0[6] = f2bf(x1.z); v0[7] = f2bf(x1.w);
    v1[0] = f2bf(x2.x); v1[1] = f2bf(x2.y); v1[2] = f2bf(x2.z); v1[3] = f2bf(x2.w);
    v1[4] = f2bf(x3.x); v1[5] = f2bf(x3.y); v1[6] = f2bf(x3.z); v1[7] = f2bf(x3.w);
    *(bf16x8*)aW = v0;
    *(bf16x8*)(aW + 8) = v1;
    __syncthreads();
    bf16x8 af[4], bfv[4];
#pragma unroll
    for (int m = 0; m < 4; ++m) af[m] = *(const bf16x8*)(aR + m * 512);
#pragma unroll
    for (int n = 0; n < 4; ++n) bfv[n] = *(const bf16x8*)(bR + n * 512);
#pragma unroll
    for (int m = 0; m < 4; ++m)
#pragma unroll
      for (int n = 0; n < 4; ++n)
        acc[m][n] = __builtin_amdgcn_mfma_f32_16x16x32_bf16(af[m], bfv[n], acc[m][n], 0, 0, 0);
    __syncthreads();
  }
#pragma unroll
  for (int m = 0; m < 4; ++m) {
#pragma unroll
    for (int n = 0; n < 4; ++n) {
      int c = col0 + wc * 64 + n * 16 + lrow;
      int h = c >> 6, hc = c & 63;
      float bval = bias[c];
#pragma unroll
      for (int i = 0; i < 4; ++i) {
        int r = row0 + wr * 64 + m * 16 + lhi * 4 + i;
        int b = r >> 11, s = r & 2047;
        float val = acc[m][n][i] + bval;
        if (z == 0) val *= QSCL;
        if (z == 2) vt[((size_t)(b * NH + h) * HD + hc) * SEQ + s] = f2bf(val);
        else {
          short* o = z == 0 ? qb : kb;
          o[((size_t)(b * NH + h) * SEQ + s) * HD + hc] = f2bf(val);
        }
      }
    }
  }
}

// Flash attention, swapped-operand 32x32x16, fully in-register softmax (m214 port).
// 4 waves x 32 q-rows = 128 q/block. KV tiles of 64. LDS 16KB single-buffered,
// staged via global_load_lds with pre-swizzled source + XOR-swizzled reads.
// Per lane: q = lane&31 stays the P/O column -> m,l,rescale are per-lane scalars.
__global__ __launch_bounds__(256) void attn_kernel(
    const short* __restrict__ qb, const short* __restrict__ kb,
    const short* __restrict__ vt, short* __restrict__ ob) {
  int qt = blockIdx.x, h = blockIdx.y, bz = blockIdx.z;
  int t = threadIdx.x, wid = t >> 6, lane = t & 63;
  int l31 = lane & 31, hi = lane >> 5;

  __shared__ __align__(16) short kl[64 * 64];  // [kpos][d], block-swizzled
  __shared__ __align__(16) short vl[64 * 64];  // [d][kpos], block-swizzled

  size_t bh = (size_t)(bz * NH + h);
  const short* kbase = kb + bh * (size_t)SEQ * HD;
  const short* vbase = vt + bh * (size_t)HD * SEQ;

  // Q fragments (B operand of swapped QK^T): col=q=lane&31, k=d=dk*16+hi*8+j
  int qg = qt * 128 + wid * 32 + l31;
  const short* qrow = qb + (bh * SEQ + qg) * HD + hi * 8;
  bf16x8 qf0 = *(const bf16x8*)(qrow);
  bf16x8 qf1 = *(const bf16x8*)(qrow + 16);
  bf16x8 qf2 = *(const bf16x8*)(qrow + 32);
  bf16x8 qf3 = *(const bf16x8*)(qrow + 48);

  // staging: wave w rows 16w..16w+15; lane L -> row 16w+(L>>3), 16B block L&7.
  // LDS dest linear (= wave base + 16B*lane); global SOURCE pre-swizzled.
  int srow = wid * 16 + (lane >> 3);
  int swc = ((lane & 7) ^ (srow & 7)) * 8;
  const short* kg = kbase + (size_t)srow * HD + swc;
  const short* vg = vbase + (size_t)srow * SEQ + swc;
  short* klA = kl + wid * 1024; short* klB = klA + 512;
  short* vlA = vl + wid * 1024; short* vlB = vlA + 512;

  f32x16 o0, o1;
#pragma unroll
  for (int i = 0; i < 16; ++i) { o0[i] = 0.f; o1[i] = 0.f; }
  float mrun = -1e30f, lrun = 0.f;

  int ksw = (l31 & 7) << 3;  // read-side swizzle (row&7 pattern; +32 rows preserves &7)

  for (int t0 = 0; t0 < SEQ; t0 += 64) {
    gload_lds16(kg + (size_t)t0 * HD, klA);
    gload_lds16(kg + (size_t)(t0 + 8) * HD, klB);
    gload_lds16(vg + t0, vlA);
    gload_lds16(vg + t0 + 8 * SEQ, vlB);
    __syncthreads();  // compiler drains vmcnt before barrier

    // QK^T (swapped): c = mfma(A=K[kpos][d], B=Q^T[d][q]) -> P^T[kpos][q]
    f32x16 c0, c1;
#pragma unroll
    for (int i = 0; i < 16; ++i) { c0[i] = 0.f; c1[i] = 0.f; }
#pragma unroll
    for (int dk = 0; dk < 4; ++dk) {
      int col = (dk * 16 + hi * 8) ^ ksw;
      bf16x8 ka = *(const bf16x8*)&kl[l31 * 64 + col];
      bf16x8 kc = *(const bf16x8*)&kl[(32 + l31) * 64 + col];
      bf16x8 qv = dk == 0 ? qf0 : dk == 1 ? qf1 : dk == 2 ? qf2 : qf3;
      c0 = __builtin_amdgcn_mfma_f32_32x32x16_bf16(ka, qv, c0, 0, 0, 0);
      c1 = __builtin_amdgcn_mfma_f32_32x32x16_bf16(kc, qv, c1, 0, 0, 0);
    }

    // online softmax, all in-register; lane owns row q=l31 (kpos split across hi pair)
    float mx = c0[0];
#pragma unroll
    for (int i = 1; i < 16; ++i) mx = fmaxf(mx, c0[i]);
#pragma unroll
    for (int i = 0; i < 16; ++i) mx = fmaxf(mx, c1[i]);
    mx = fmaxf(mx, __shfl_xor(mx, 32));
    if (!__all(mx - mrun <= 8.f)) {  // defer-max (T13), log2 domain: P <= 2^8
      float mnew = fmaxf(mrun, mx);
      float corr = __builtin_amdgcn_exp2f(mrun - mnew);
      lrun *= corr;
#pragma unroll
      for (int i = 0; i < 16; ++i) { o0[i] *= corr; o1[i] *= corr; }
      mrun = mnew;
    }
#pragma unroll
    for (int i = 0; i < 16; ++i) c0[i] = __builtin_amdgcn_exp2f(c0[i] - mrun);
#pragma unroll
    for (int i = 0; i < 16; ++i) c1[i] = __builtin_amdgcn_exp2f(c1[i] - mrun);
    float ps = 0.f;
#pragma unroll
    for (int i = 0; i < 16; ++i) ps += c0[i];
#pragma unroll
    for (int i = 0; i < 16; ++i) ps += c1[i];
    ps += __shfl_xor(ps, 32);
    lrun += ps;

    // pack P to bf16 pairs + hi-half exchange -> PV fragments (T12 structure)
    // reg r of block b: kpos = b*32 + (r&3) + 8*(r>>2) + 4*hi
    unsigned u0 = pk2(c0[0], c0[1]),   u1 = pk2(c0[2], c0[3]);
    unsigned u2 = pk2(c0[4], c0[5]),   u3 = pk2(c0[6], c0[7]);
    unsigned u4 = pk2(c0[8], c0[9]),   u5 = pk2(c0[10], c0[11]);
    unsigned u6 = pk2(c0[12], c0[13]), u7 = pk2(c0[14], c0[15]);
    unsigned w0 = pk2(c1[0], c1[1]),   w1 = pk2(c1[2], c1[3]);
    unsigned w2 = pk2(c1[4], c1[5]),   w3 = pk2(c1[6], c1[7]);
    unsigned w4 = pk2(c1[8], c1[9]),   w5 = pk2(c1[10], c1[11]);
    unsigned w6 = pk2(c1[12], c1[13]), w7 = pk2(c1[14], c1[15]);
    unsigned x0 = __shfl_xor(u0, 32), x1 = __shfl_xor(u1, 32);
    unsigned x2 = __shfl_xor(u2, 32), x3 = __shfl_xor(u3, 32);
    unsigned x4 = __shfl_xor(u4, 32), x5 = __shfl_xor(u5, 32);
    unsigned x6 = __shfl_xor(u6, 32), x7 = __shfl_xor(u7, 32);
    unsigned y0 = __shfl_xor(w0, 32), y1 = __shfl_xor(w1, 32);
    unsigned y2 = __shfl_xor(w2, 32), y3 = __shfl_xor(w3, 32);
    unsigned y4 = __shfl_xor(w4, 32), y5 = __shfl_xor(w5, 32);
    unsigned y6 = __shfl_xor(w6, 32), y7 = __shfl_xor(w7, 32);
    // frag for k-chunk: lane needs P^T[k=8hi+j][q], assembled from own+partner pairs
    bf16x8 fA0 = mkfrag(hi ? x2 : u0, hi ? x3 : u1, hi ? u2 : x0, hi ? u3 : x1);  // k 0..15
    bf16x8 fA1 = mkfrag(hi ? x6 : u4, hi ? x7 : u5, hi ? u6 : x4, hi ? u7 : x5);  // k 16..31
    bf16x8 fB0 = mkfrag(hi ? y2 : w0, hi ? y3 : w1, hi ? w2 : y0, hi ? w3 : y1);  // k 32..47
    bf16x8 fB1 = mkfrag(hi ? y6 : w4, hi ? y7 : w5, hi ? w6 : y4, hi ? w7 : y5);  // k 48..63

    // PV (swapped): o = mfma(A=V^T[d][k], B=P^T[k][q]) -> O^T[d][q], q=lane&31
#pragma unroll
    for (int kc4 = 0; kc4 < 4; ++kc4) {
      bf16x8 pf = kc4 == 0 ? fA0 : kc4 == 1 ? fA1 : kc4 == 2 ? fB0 : fB1;
      int col = (kc4 * 16 + hi * 8) ^ ksw;
      bf16x8 va = *(const bf16x8*)&vl[l31 * 64 + col];
      bf16x8 vb = *(const bf16x8*)&vl[(32 + l31) * 64 + col];
      o0 = __builtin_amdgcn_mfma_f32_32x32x16_bf16(va, pf, o0, 0, 0, 0);
      o1 = __builtin_amdgcn_mfma_f32_32x32x16_bf16(vb, pf, o1, 0, 0, 0);
    }
    __syncthreads();
  }

  float inv = 1.0f / lrun;
  short* orow = ob + ((size_t)(bz * SEQ + qg)) * DIN + h * HD;
#pragma unroll
  for (int r = 0; r < 16; ++r) {
    int d = (r & 3) + 8 * (r >> 2) + 4 * hi;
    orow[d] = f2bf(o0[r] * inv);
    orow[32 + d] = f2bf(o1[r] * inv);
  }
}

// out projection: 128x128-tile GEMM, fp32 out + bias
__global__ __launch_bounds__(256) void oproj_kernel(
    const short* __restrict__ ob, const short* __restrict__ wto,
    const float* __restrict__ bo, float* __restrict__ out) {
  int mt = blockIdx.x, nt = blockIdx.y;
  __shared__ __align__(16) short Al[128 * 32];
  __shared__ __align__(16) short Bl[128 * 32];
  int t = threadIdx.x, wid = t >> 6, lane = t & 63;
  int lrow = lane & 15, lhi = lane >> 4;
  int wr = wid >> 1, wc = wid & 1;
  int row0 = mt * 128, col0 = nt * 128;

  const short* aG = ob + (size_t)(row0 + wid * 16 + (lane >> 2)) * DIN + (lane & 3) * 8;
  const short* bG = wto + (size_t)(col0 + wid * 16 + (lane >> 2)) * DIN + (lane & 3) * 8;
  short* aL0 = &Al[wid * 512];
  short* aL1 = &Al[(4 + wid) * 512];
  short* bL0 = &Bl[wid * 512];
  short* bL1 = &Bl[(4 + wid) * 512];
  const short* aR = &Al[(wr * 64 + lrow) * 32 + lhi * 8];
  const short* bR = &Bl[(wc * 64 + lrow) * 32 + lhi * 8];

  f32x4 acc[4][4] = {};
  for (int kk = 0; kk < DIN; kk += 32) {
    gload_lds16(aG + kk, aL0);
    gload_lds16(aG + 64 * DIN + kk, aL1);
    gload_lds16(bG + kk, bL0);
    gload_lds16(bG + 64 * DIN + kk, bL1);
    __syncthreads();
    bf16x8 af[4], bfv[4];
#pragma unroll
    for (int m = 0; m < 4; ++m) af[m] = *(const bf16x8*)(aR + m * 512);
#pragma unroll
    for (int n = 0; n < 4; ++n) bfv[n] = *(const bf16x8*)(bR + n * 512);
#pragma unroll
    for (int m = 0; m < 4; ++m)
#pragma unroll
      for (int n = 0; n < 4; ++n)
        acc[m][n] = __builtin_amdgcn_mfma_f32_16x16x32_bf16(af[m], bfv[n], acc[m][n], 0, 0, 0);
    __syncthreads();
  }
#pragma unroll
  for (int m = 0; m < 4; ++m) {
#pragma unroll
    for (int n = 0; n < 4; ++n) {
      int c = col0 + wc * 64 + n * 16 + lrow;
      float bval = bo[c];
#pragma unroll
      for (int i = 0; i < 4; ++i) {
        int r = row0 + wr * 64 + m * 16 + lhi * 4 + i;
        out[(size_t)r * DIN + c] = acc[m][n][i] + bval;
      }
    }
  }
}

extern "C" void kernel_launch(void* const* d_in, const int* in_sizes, int n_in,
                              void* d_out, int out_size, void* d_ws, size_t ws_size,
                              hipStream_t stream) {
  const float* Q  = (const float*)d_in[0];
  const float* K  = (const float*)d_in[1];
  const float* V  = (const float*)d_in[2];
  const float* Wq = (const float*)d_in[3];
  const float* bq = (const float*)d_in[4];
  const float* Wk = (const float*)d_in[5];
  const float* bk = (const float*)d_in[6];
  const float* Wv = (const float*)d_in[7];
  const float* bv = (const float*)d_in[8];
  const float* Wo = (const float*)d_in[9];
  const float* bo = (const float*)d_in[10];
  float* out = (float*)d_out;

  short* ws = (short*)d_ws;
  const size_t NX = (size_t)NB * SEQ * DIN;        // 4194304 elems (8 MiB bf16)
  const size_t NW = (size_t)NH * HD * DIN;         // 1048576
  short* qbuf = ws;
  short* kbuf = qbuf + NX;
  short* vtb  = kbuf + NX;
  short* obuf = vtb + NX;
  short* wtq  = obuf + NX;   // [3][H][64][1024] combined
  short* wto  = wtq + 3 * NW;
  short* xq = wto + NW;
  short* xk = xq + NX;
  short* xv = xk + NX;
  const size_t need_big = (7 * NX + 4 * NW) * sizeof(short);  // 64 MiB

  wt3_kernel<<<dim3(1, 16, 48), 256, 0, stream>>>(Wq, Wk, Wv, wtq);
  wt_kernel<<<dim3(16, 16, 1), 256, 0, stream>>>(Wo, wto, DIN, DIN);
  if (ws_size >= need_big) {
    cvt_kernel<<<dim3(2048, 3), 256, 0, stream>>>(Q, K, V, xq, xk, xv);
    proj_bf16_kernel<<<dim3(32, 8, 3), 256, 0, stream>>>(xq, xk, xv, wtq, bq, bk, bv,
                                                         qbuf, kbuf, vtb);
  } else {
    proj_f32_kernel<<<dim3(32, 8, 3), 256, 0, stream>>>(Q, K, V, wtq, bq, bk, bv,
                                                        qbuf, kbuf, vtb);
  }
  attn_kernel<<<dim3(16, 16, 2), 256, 0, stream>>>(qbuf, kbuf, vtb, obuf);
  oproj_kernel<<<dim3(32, 8), 256, 0, stream>>>(obuf, wto, bo, out);
}

// Round 6
// 245.441 us; speedup vs baseline: 1.4616x; 1.0185x over previous
//
#include <hip/hip_runtime.h>
#include <hip/hip_bf16.h>

#define DIN 1024
#define NH 16
#define HD 64
#define SEQ 2048
#define NB 2

typedef __attribute__((ext_vector_type(8))) short bf16x8;
typedef __attribute__((ext_vector_type(4))) float f32x4;
typedef __attribute__((ext_vector_type(16))) float f32x16;

__device__ inline short f2bf(float f) {
  union { float f; unsigned u; } v; v.f = f;
  unsigned r = v.u + 0x7fff + ((v.u >> 16) & 1);
  return (short)(r >> 16);
}

// 2x f32 -> packed bf16 pair (lo, hi) in one instruction (T12 recipe)
__device__ inline unsigned pk2(float lo, float hi) {
  unsigned r;
  asm("v_cvt_pk_bf16_f32 %0, %1, %2" : "=v"(r) : "v"(lo), "v"(hi));
  return r;
}

union U8 { unsigned u[4]; bf16x8 v; };
__device__ inline bf16x8 mkfrag(unsigned a, unsigned b, unsigned c, unsigned d) {
  U8 x; x.u[0] = a; x.u[1] = b; x.u[2] = c; x.u[3] = d; return x.v;
}

__device__ __forceinline__ void gload_lds16(const void* g, void* l) {
  __builtin_amdgcn_global_load_lds(
      (const __attribute__((address_space(1))) unsigned*)g,
      (__attribute__((address_space(3))) unsigned*)l, 16, 0, 0);
}

// fp32 Q/K/V [4096][1024] -> bf16, vectorized 8/thread
__global__ __launch_bounds__(256) void cvt_kernel(
    const float* __restrict__ Q, const float* __restrict__ K, const float* __restrict__ V,
    short* __restrict__ xq, short* __restrict__ xk, short* __restrict__ xv) {
  int z = blockIdx.y;
  const float* src = z == 0 ? Q : (z == 1 ? K : V);
  short* dst = z == 0 ? xq : (z == 1 ? xk : xv);
  size_t e = ((size_t)blockIdx.x * 256 + threadIdx.x) * 8;
  float4 x0 = *(const float4*)(src + e);
  float4 x1 = *(const float4*)(src + e + 4);
  bf16x8 v;
  v[0] = f2bf(x0.x); v[1] = f2bf(x0.y); v[2] = f2bf(x0.z); v[3] = f2bf(x0.w);
  v[4] = f2bf(x1.x); v[5] = f2bf(x1.y); v[6] = f2bf(x1.z); v[7] = f2bf(x1.w);
  *(bf16x8*)(dst + e) = v;
}

// Wq/Wk/Wv [H][1024][64] fp32 -> Wt [3][H][64][1024] bf16 (transposed per head)
__global__ __launch_bounds__(256) void wt3_kernel(
    const float* __restrict__ Wq, const float* __restrict__ Wk, const float* __restrict__ Wv,
    short* __restrict__ out) {
  int zz = blockIdx.z; int which = zz >> 4, h = zz & 15;
  const float* in = (which == 0 ? Wq : (which == 1 ? Wk : Wv)) + (size_t)h * (DIN * HD);
  short* o = out + (size_t)which * (NH * HD * DIN) + (size_t)h * (HD * DIN);
  __shared__ float tile[64][65];
  int r0 = blockIdx.y * 64;
  int t = threadIdx.x;
  int r = t >> 2, cc = (t & 3) * 16;
#pragma unroll
  for (int j = 0; j < 16; ++j) tile[r][cc + j] = in[(size_t)(r0 + r) * HD + cc + j];
  __syncthreads();
  int c = t >> 2, rr = (t & 3) * 16;
#pragma unroll
  for (int j = 0; j < 16; ++j) o[(size_t)c * DIN + r0 + rr + j] = f2bf(tile[rr + j][c]);
}

// Wo [1024][1024] fp32 -> Wot [1024 n][1024 k] bf16
__global__ __launch_bounds__(256) void wt_kernel(const float* __restrict__ in,
                                                 short* __restrict__ out, int R, int C) {
  __shared__ float tile[64][65];
  int r0 = blockIdx.y * 64, c0 = blockIdx.x * 64;
  int t = threadIdx.x;
  int r = t >> 2, cc = (t & 3) * 16;
#pragma unroll
  for (int j = 0; j < 16; ++j) tile[r][cc + j] = in[(size_t)(r0 + r) * C + c0 + cc + j];
  __syncthreads();
  int c = t >> 2, rr = (t & 3) * 16;
#pragma unroll
  for (int j = 0; j < 16; ++j) out[(size_t)(c0 + c) * R + r0 + rr + j] = f2bf(tile[rr + j][c]);
}

#define QSCL 0.18033688011112042f  // 0.125 * log2(e), folded into q at proj time

// 128x128-tile GEMM (m97): A bf16 + B bf16 both via global_load_lds.
__global__ __launch_bounds__(256) void proj_bf16_kernel(
    const short* __restrict__ xq, const short* __restrict__ xk, const short* __restrict__ xv,
    const short* __restrict__ wt,
    const float* __restrict__ bq, const float* __restrict__ bk, const float* __restrict__ bv,
    short* __restrict__ qb, short* __restrict__ kb, short* __restrict__ vt) {
  int mt = blockIdx.x, nt = blockIdx.y, z = blockIdx.z;
  const short* A = z == 0 ? xq : (z == 1 ? xk : xv);
  const short* Bt = wt + (size_t)z * (DIN * DIN);
  const float* bias = z == 0 ? bq : (z == 1 ? bk : bv);

  __shared__ __align__(16) short Al[128 * 32];
  __shared__ __align__(16) short Bl[128 * 32];

  int t = threadIdx.x, wid = t >> 6, lane = t & 63;
  int lrow = lane & 15, lhi = lane >> 4;
  int wr = wid >> 1, wc = wid & 1;
  int row0 = mt * 128, col0 = nt * 128;

  const short* aG = A + (size_t)(row0 + wid * 16 + (lane >> 2)) * DIN + (lane & 3) * 8;
  const short* bG = Bt + (size_t)(col0 + wid * 16 + (lane >> 2)) * DIN + (lane & 3) * 8;
  short* aL0 = &Al[wid * 512];
  short* aL1 = &Al[(4 + wid) * 512];
  short* bL0 = &Bl[wid * 512];
  short* bL1 = &Bl[(4 + wid) * 512];
  const short* aR = &Al[(wr * 64 + lrow) * 32 + lhi * 8];
  const short* bR = &Bl[(wc * 64 + lrow) * 32 + lhi * 8];

  f32x4 acc[4][4] = {};
  for (int kk = 0; kk < DIN; kk += 32) {
    gload_lds16(aG + kk, aL0);
    gload_lds16(aG + 64 * DIN + kk, aL1);
    gload_lds16(bG + kk, bL0);
    gload_lds16(bG + 64 * DIN + kk, bL1);
    __syncthreads();
    bf16x8 af[4], bfv[4];
#pragma unroll
    for (int m = 0; m < 4; ++m) af[m] = *(const bf16x8*)(aR + m * 512);
#pragma unroll
    for (int n = 0; n < 4; ++n) bfv[n] = *(const bf16x8*)(bR + n * 512);
#pragma unroll
    for (int m = 0; m < 4; ++m)
#pragma unroll
      for (int n = 0; n < 4; ++n)
        acc[m][n] = __builtin_amdgcn_mfma_f32_16x16x32_bf16(af[m], bfv[n], acc[m][n], 0, 0, 0);
    __syncthreads();
  }

#pragma unroll
  for (int m = 0; m < 4; ++m) {
#pragma unroll
    for (int n = 0; n < 4; ++n) {
      int c = col0 + wc * 64 + n * 16 + lrow;
      int h = c >> 6, hc = c & 63;
      float bval = bias[c];
#pragma unroll
      for (int i = 0; i < 4; ++i) {
        int r = row0 + wr * 64 + m * 16 + lhi * 4 + i;
        int b = r >> 11, s = r & 2047;
        float val = acc[m][n][i] + bval;
        if (z == 0) val *= QSCL;
        if (z == 2) vt[((size_t)(b * NH + h) * HD + hc) * SEQ + s] = f2bf(val);
        else {
          short* o = z == 0 ? qb : kb;
          o[((size_t)(b * NH + h) * SEQ + s) * HD + hc] = f2bf(val);
        }
      }
    }
  }
}

// fallback (40 MiB ws): fp32 A reg-staged + cvt in-loop
__global__ __launch_bounds__(256) void proj_f32_kernel(
    const float* __restrict__ Q, const float* __restrict__ K, const float* __restrict__ V,
    const short* __restrict__ wt,
    const float* __restrict__ bq, const float* __restrict__ bk, const float* __restrict__ bv,
    short* __restrict__ qb, short* __restrict__ kb, short* __restrict__ vt) {
  int mt = blockIdx.x, nt = blockIdx.y, z = blockIdx.z;
  const float* X = z == 0 ? Q : (z == 1 ? K : V);
  const short* Bt = wt + (size_t)z * (DIN * DIN);
  const float* bias = z == 0 ? bq : (z == 1 ? bk : bv);

  __shared__ __align__(16) short Al[128 * 32];
  __shared__ __align__(16) short Bl[128 * 32];

  int t = threadIdx.x, wid = t >> 6, lane = t & 63;
  int lrow = lane & 15, lhi = lane >> 4;
  int wr = wid >> 1, wc = wid & 1;
  int row0 = mt * 128, col0 = nt * 128;

  int arow = t >> 1, acol = (t & 1) * 16;
  const float* aF = X + (size_t)(row0 + arow) * DIN + acol;
  short* aW = &Al[arow * 32 + acol];

  const short* bG = Bt + (size_t)(col0 + wid * 16 + (lane >> 2)) * DIN + (lane & 3) * 8;
  short* bL0 = &Bl[wid * 512];
  short* bL1 = &Bl[(4 + wid) * 512];

  const short* aR = &Al[(wr * 64 + lrow) * 32 + lhi * 8];
  const short* bR = &Bl[(wc * 64 + lrow) * 32 + lhi * 8];

  f32x4 acc[4][4] = {};
  for (int kk = 0; kk < DIN; kk += 32) {
    gload_lds16(bG + kk, bL0);
    gload_lds16(bG + 64 * DIN + kk, bL1);
    float4 x0 = *(const float4*)(aF + kk);
    float4 x1 = *(const float4*)(aF + kk + 4);
    float4 x2 = *(const float4*)(aF + kk + 8);
    float4 x3 = *(const float4*)(aF + kk + 12);
    bf16x8 v0, v1;
    v0[0] = f2bf(x0.x); v0[1] = f2bf(x0.y); v0[2] = f2bf(x0.z); v0[3] = f2bf(x0.w);
    v0[4] = f2bf(x1.x); v0[5] = f2bf(x1.y); v0[6] = f2bf(x1.z); v0[7] = f2bf(x1.w);
    v1[0] = f2bf(x2.x); v1[1] = f2bf(x2.y); v1[2] = f2bf(x2.z); v1[3] = f2bf(x2.w);
    v1[4] = f2bf(x3.x); v1[5] = f2bf(x3.y); v1[6] = f2bf(x3.z); v1[7] = f2bf(x3.w);
    *(bf16x8*)aW = v0;
    *(bf16x8*)(aW + 8) = v1;
    __syncthreads();
    bf16x8 af[4], bfv[4];
#pragma unroll
    for (int m = 0; m < 4; ++m) af[m] = *(const bf16x8*)(aR + m * 512);
#pragma unroll
    for (int n = 0; n < 4; ++n) bfv[n] = *(const bf16x8*)(bR + n * 512);
#pragma unroll
    for (int m = 0; m < 4; ++m)
#pragma unroll
      for (int n = 0; n < 4; ++n)
        acc[m][n] = __builtin_amdgcn_mfma_f32_16x16x32_bf16(af[m], bfv[n], acc[m][n], 0, 0, 0);
    __syncthreads();
  }
#pragma unroll
  for (int m = 0; m < 4; ++m) {
#pragma unroll
    for (int n = 0; n < 4; ++n) {
      int c = col0 + wc * 64 + n * 16 + lrow;
      int h = c >> 6, hc = c & 63;
      float bval = bias[c];
#pragma unroll
      for (int i = 0; i < 4; ++i) {
        int r = row0 + wr * 64 + m * 16 + lhi * 4 + i;
        int b = r >> 11, s = r & 2047;
        float val = acc[m][n][i] + bval;
        if (z == 0) val *= QSCL;
        if (z == 2) vt[((size_t)(b * NH + h) * HD + hc) * SEQ + s] = f2bf(val);
        else {
          short* o = z == 0 ? qb : kb;
          o[((size_t)(b * NH + h) * SEQ + s) * HD + hc] = f2bf(val);
        }
      }
    }
  }
}

// Flash attention, swapped-operand 32x32x16, in-register softmax.
// 4 waves x 32 q-rows = 128 q/block. KV tiles of 64.
// K/V double-buffered (stage-early overlap, T3-min), cvt_pk packing, tree reduce.
__global__ __launch_bounds__(256) void attn_kernel(
    const short* __restrict__ qb, const short* __restrict__ kb,
    const short* __restrict__ vt, short* __restrict__ ob) {
  int qt = blockIdx.x, h = blockIdx.y, bz = blockIdx.z;
  int t = threadIdx.x, wid = t >> 6, lane = t & 63;
  int l31 = lane & 31, hi = lane >> 5;

  __shared__ __align__(16) short kl[2][64 * 64];
  __shared__ __align__(16) short vl[2][64 * 64];

  size_t bh = (size_t)(bz * NH + h);
  const short* kbase = kb + bh * (size_t)SEQ * HD;
  const short* vbase = vt + bh * (size_t)HD * SEQ;

  int qg = qt * 128 + wid * 32 + l31;
  const short* qrow = qb + (bh * SEQ + qg) * HD + hi * 8;
  bf16x8 qf0 = *(const bf16x8*)(qrow);
  bf16x8 qf1 = *(const bf16x8*)(qrow + 16);
  bf16x8 qf2 = *(const bf16x8*)(qrow + 32);
  bf16x8 qf3 = *(const bf16x8*)(qrow + 48);

  // staging: wave w rows 16w..16w+15; LDS dest linear, global SOURCE pre-swizzled.
  int srow = wid * 16 + (lane >> 3);
  int swc = ((lane & 7) ^ (srow & 7)) * 8;
  const short* kg = kbase + (size_t)srow * HD + swc;
  const short* vg = vbase + (size_t)srow * SEQ + swc;

  f32x16 o0, o1;
#pragma unroll
  for (int i = 0; i < 16; ++i) { o0[i] = 0.f; o1[i] = 0.f; }
  float mrun = -1e30f, lrun = 0.f;

  int ksw = (l31 & 7) << 3;  // read-side swizzle

#define STAGE(T0, B)                                                   \
  do {                                                                 \
    gload_lds16(kg + (size_t)(T0)*HD, &kl[B][wid * 1024]);             \
    gload_lds16(kg + (size_t)((T0) + 8) * HD, &kl[B][wid * 1024 + 512]); \
    gload_lds16(vg + (T0), &vl[B][wid * 1024]);                        \
    gload_lds16(vg + (T0) + 8 * SEQ, &vl[B][wid * 1024 + 512]);        \
  } while (0)

  STAGE(0, 0);
  __syncthreads();  // drains vmcnt(0): tile 0 ready
  int cur = 0;

  for (int t0 = 0; t0 < SEQ; t0 += 64) {
    if (t0 + 64 < SEQ) STAGE(t0 + 64, cur ^ 1);  // issue early, lands during compute

    // QK^T (swapped): P^T[kpos][q]
    f32x16 c0, c1;
#pragma unroll
    for (int i = 0; i < 16; ++i) { c0[i] = 0.f; c1[i] = 0.f; }
#pragma unroll
    for (int dk = 0; dk < 4; ++dk) {
      int col = (dk * 16 + hi * 8) ^ ksw;
      bf16x8 ka = *(const bf16x8*)&kl[cur][l31 * 64 + col];
      bf16x8 kc = *(const bf16x8*)&kl[cur][(32 + l31) * 64 + col];
      bf16x8 qv = dk == 0 ? qf0 : dk == 1 ? qf1 : dk == 2 ? qf2 : qf3;
      c0 = __builtin_amdgcn_mfma_f32_32x32x16_bf16(ka, qv, c0, 0, 0, 0);
      c1 = __builtin_amdgcn_mfma_f32_32x32x16_bf16(kc, qv, c1, 0, 0, 0);
    }

    // online softmax, in-register; tree max (depth 5, not 31)
    float tm[16];
#pragma unroll
    for (int i = 0; i < 16; ++i) tm[i] = fmaxf(c0[i], c1[i]);
#pragma unroll
    for (int i = 0; i < 8; ++i) tm[i] = fmaxf(tm[i], tm[i + 8]);
#pragma unroll
    for (int i = 0; i < 4; ++i) tm[i] = fmaxf(tm[i], tm[i + 4]);
    float mx = fmaxf(fmaxf(tm[0], tm[1]), fmaxf(tm[2], tm[3]));
    mx = fmaxf(mx, __shfl_xor(mx, 32));
    if (!__all(mx - mrun <= 8.f)) {  // defer-max (T13)
      float mnew = fmaxf(mrun, mx);
      float corr = __builtin_amdgcn_exp2f(mrun - mnew);
      lrun *= corr;
#pragma unroll
      for (int i = 0; i < 16; ++i) { o0[i] *= corr; o1[i] *= corr; }
      mrun = mnew;
    }
#pragma unroll
    for (int i = 0; i < 16; ++i) c0[i] = __builtin_amdgcn_exp2f(c0[i] - mrun);
#pragma unroll
    for (int i = 0; i < 16; ++i) c1[i] = __builtin_amdgcn_exp2f(c1[i] - mrun);
    float ts[16];
#pragma unroll
    for (int i = 0; i < 16; ++i) ts[i] = c0[i] + c1[i];
#pragma unroll
    for (int i = 0; i < 8; ++i) ts[i] += ts[i + 8];
#pragma unroll
    for (int i = 0; i < 4; ++i) ts[i] += ts[i + 4];
    float ps = (ts[0] + ts[1]) + (ts[2] + ts[3]);
    ps += __shfl_xor(ps, 32);
    lrun += ps;

    // pack P to bf16 (v_cvt_pk) + hi-half exchange -> PV fragments
    unsigned u0 = pk2(c0[0], c0[1]),   u1 = pk2(c0[2], c0[3]);
    unsigned u2 = pk2(c0[4], c0[5]),   u3 = pk2(c0[6], c0[7]);
    unsigned u4 = pk2(c0[8], c0[9]),   u5 = pk2(c0[10], c0[11]);
    unsigned u6 = pk2(c0[12], c0[13]), u7 = pk2(c0[14], c0[15]);
    unsigned w0 = pk2(c1[0], c1[1]),   w1 = pk2(c1[2], c1[3]);
    unsigned w2 = pk2(c1[4], c1[5]),   w3 = pk2(c1[6], c1[7]);
    unsigned w4 = pk2(c1[8], c1[9]),   w5 = pk2(c1[10], c1[11]);
    unsigned w6 = pk2(c1[12], c1[13]), w7 = pk2(c1[14], c1[15]);
    unsigned x0 = __shfl_xor(u0, 32), x1 = __shfl_xor(u1, 32);
    unsigned x2 = __shfl_xor(u2, 32), x3 = __shfl_xor(u3, 32);
    unsigned x4 = __shfl_xor(u4, 32), x5 = __shfl_xor(u5, 32);
    unsigned x6 = __shfl_xor(u6, 32), x7 = __shfl_xor(u7, 32);
    unsigned y0 = __shfl_xor(w0, 32), y1 = __shfl_xor(w1, 32);
    unsigned y2 = __shfl_xor(w2, 32), y3 = __shfl_xor(w3, 32);
    unsigned y4 = __shfl_xor(w4, 32), y5 = __shfl_xor(w5, 32);
    unsigned y6 = __shfl_xor(w6, 32), y7 = __shfl_xor(w7, 32);
    bf16x8 fA0 = mkfrag(hi ? x2 : u0, hi ? x3 : u1, hi ? u2 : x0, hi ? u3 : x1);
    bf16x8 fA1 = mkfrag(hi ? x6 : u4, hi ? x7 : u5, hi ? u6 : x4, hi ? u7 : x5);
    bf16x8 fB0 = mkfrag(hi ? y2 : w0, hi ? y3 : w1, hi ? w2 : y0, hi ? w3 : y1);
    bf16x8 fB1 = mkfrag(hi ? y6 : w4, hi ? y7 : w5, hi ? w6 : y4, hi ? w7 : y5);

    // PV (swapped): O^T[d][q]
#pragma unroll
    for (int kc4 = 0; kc4 < 4; ++kc4) {
      bf16x8 pf = kc4 == 0 ? fA0 : kc4 == 1 ? fA1 : kc4 == 2 ? fB0 : fB1;
      int col = (kc4 * 16 + hi * 8) ^ ksw;
      bf16x8 va = *(const bf16x8*)&vl[cur][l31 * 64 + col];
      bf16x8 vb = *(const bf16x8*)&vl[cur][(32 + l31) * 64 + col];
      o0 = __builtin_amdgcn_mfma_f32_32x32x16_bf16(va, pf, o0, 0, 0, 0);
      o1 = __builtin_amdgcn_mfma_f32_32x32x16_bf16(vb, pf, o1, 0, 0, 0);
    }
    __syncthreads();  // drains next-tile stage (overlapped) + protects buffer swap
    cur ^= 1;
  }
#undef STAGE

  float inv = 1.0f / lrun;
  short* orow = ob + ((size_t)(bz * SEQ + qg)) * DIN + h * HD;
#pragma unroll
  for (int r = 0; r < 16; ++r) {
    int d = (r & 3) + 8 * (r >> 2) + 4 * hi;
    orow[d] = f2bf(o0[r] * inv);
    orow[32 + d] = f2bf(o1[r] * inv);
  }
}

// out projection: 64x128-tile GEMM (512 blocks = 2/CU), fp32 out + bias
__global__ __launch_bounds__(256) void oproj_kernel(
    const short* __restrict__ ob, const short* __restrict__ wto,
    const float* __restrict__ bo, float* __restrict__ out) {
  int mt = blockIdx.x, nt = blockIdx.y;
  __shared__ __align__(16) short Al[64 * 32];
  __shared__ __align__(16) short Bl[128 * 32];
  int t = threadIdx.x, wid = t >> 6, lane = t & 63;
  int lrow = lane & 15, lhi = lane >> 4;
  int wr = wid >> 1, wc = wid & 1;  // wave: rows wr*32..+31, cols wc*64..+63
  int row0 = mt * 64, col0 = nt * 128;

  const short* aG = ob + (size_t)(row0 + wid * 16 + (lane >> 2)) * DIN + (lane & 3) * 8;
  const short* bG = wto + (size_t)(col0 + wid * 16 + (lane >> 2)) * DIN + (lane & 3) * 8;
  short* aL = &Al[wid * 512];
  short* bL0 = &Bl[wid * 512];
  short* bL1 = &Bl[(4 + wid) * 512];
  const short* aR = &Al[(wr * 32 + lrow) * 32 + lhi * 8];
  const short* bR = &Bl[(wc * 64 + lrow) * 32 + lhi * 8];

  f32x4 acc[2][4] = {};
  for (int kk = 0; kk < DIN; kk += 32) {
    gload_lds16(aG + kk, aL);
    gload_lds16(bG + kk, bL0);
    gload_lds16(bG + 64 * DIN + kk, bL1);
    __syncthreads();
    bf16x8 af[2], bfv[4];
#pragma unroll
    for (int m = 0; m < 2; ++m) af[m] = *(const bf16x8*)(aR + m * 512);
#pragma unroll
    for (int n = 0; n < 4; ++n) bfv[n] = *(const bf16x8*)(bR + n * 512);
#pragma unroll
    for (int m = 0; m < 2; ++m)
#pragma unroll
      for (int n = 0; n < 4; ++n)
        acc[m][n] = __builtin_amdgcn_mfma_f32_16x16x32_bf16(af[m], bfv[n], acc[m][n], 0, 0, 0);
    __syncthreads();
  }
#pragma unroll
  for (int m = 0; m < 2; ++m) {
#pragma unroll
    for (int n = 0; n < 4; ++n) {
      int c = col0 + wc * 64 + n * 16 + lrow;
      float bval = bo[c];
#pragma unroll
      for (int i = 0; i < 4; ++i) {
        int r = row0 + wr * 32 + m * 16 + lhi * 4 + i;
        out[(size_t)r * DIN + c] = acc[m][n][i] + bval;
      }
    }
  }
}

extern "C" void kernel_launch(void* const* d_in, const int* in_sizes, int n_in,
                              void* d_out, int out_size, void* d_ws, size_t ws_size,
                              hipStream_t stream) {
  const float* Q  = (const float*)d_in[0];
  const float* K  = (const float*)d_in[1];
  const float* V  = (const float*)d_in[2];
  const float* Wq = (const float*)d_in[3];
  const float* bq = (const float*)d_in[4];
  const float* Wk = (const float*)d_in[5];
  const float* bk = (const float*)d_in[6];
  const float* Wv = (const float*)d_in[7];
  const float* bv = (const float*)d_in[8];
  const float* Wo = (const float*)d_in[9];
  const float* bo = (const float*)d_in[10];
  float* out = (float*)d_out;

  short* ws = (short*)d_ws;
  const size_t NX = (size_t)NB * SEQ * DIN;        // 4194304 elems (8 MiB bf16)
  const size_t NW = (size_t)NH * HD * DIN;         // 1048576
  short* qbuf = ws;
  short* kbuf = qbuf + NX;
  short* vtb  = kbuf + NX;
  short* obuf = vtb + NX;
  short* wtq  = obuf + NX;   // [3][H][64][1024] combined
  short* wto  = wtq + 3 * NW;
  short* xq = wto + NW;
  short* xk = xq + NX;
  short* xv = xk + NX;
  const size_t need_big = (7 * NX + 4 * NW) * sizeof(short);  // 64 MiB

  wt3_kernel<<<dim3(1, 16, 48), 256, 0, stream>>>(Wq, Wk, Wv, wtq);
  wt_kernel<<<dim3(16, 16, 1), 256, 0, stream>>>(Wo, wto, DIN, DIN);
  if (ws_size >= need_big) {
    cvt_kernel<<<dim3(2048, 3), 256, 0, stream>>>(Q, K, V, xq, xk, xv);
    proj_bf16_kernel<<<dim3(32, 8, 3), 256, 0, stream>>>(xq, xk, xv, wtq, bq, bk, bv,
                                                         qbuf, kbuf, vtb);
  } else {
    proj_f32_kernel<<<dim3(32, 8, 3), 256, 0, stream>>>(Q, K, V, wtq, bq, bk, bv,
                                                        qbuf, kbuf, vtb);
  }
  attn_kernel<<<dim3(16, 16, 2), 256, 0, stream>>>(qbuf, kbuf, vtb, obuf);
  oproj_kernel<<<dim3(64, 8), 256, 0, stream>>>(obuf, wto, bo, out);
}